// Round 1
// baseline (231.664 us; speedup 1.0000x reference)
//
#include <hip/hip_runtime.h>
#include <stdint.h>

// Problem geometry: B=8, C=256, H=W=64 (HW=4096). Output [8,256,64,64] f32.
//
// ws layout (float offsets), total 622,592 bytes:
static constexpr size_t WS_PH_RGB  = 0;        // [8][256] normalized proto rgb
static constexpr size_t WS_PH_DEP  = 2048;     // [8][256]
static constexpr size_t WS_SIM_RGB = 4096;     // [8][4096]
static constexpr size_t WS_SIM_DEP = 36864;    // [8][4096]
static constexpr size_t WS_NPMAPS  = 69632;    // np_rgb, np_dep, np_mask, np_rdep each [4096]
static constexpr size_t WS_STATS   = 86016;    // 27 floats: S[4], G[16], V[4], mn_norm, pen_fg, pen_bg
static constexpr size_t WS_POUT    = 86048;    // 4 floats: rgb_fg, dep_fg, rgb_bg, dep_bg
static constexpr size_t WS_AB      = 90112;    // [8][4096] float2 (alpha,beta per position)

// ---------------- JAX threefry2x32 (partitionable semantics) ----------------
__device__ __forceinline__ void threefry2x32(uint32_t k0, uint32_t k1,
                                             uint32_t c0, uint32_t c1,
                                             uint32_t& o0, uint32_t& o1) {
  uint32_t ks2 = k0 ^ k1 ^ 0x1BD11BDAu;
  uint32_t x0 = c0 + k0;
  uint32_t x1 = c1 + k1;
#define TF_ROUND(r) { x0 += x1; x1 = (x1 << (r)) | (x1 >> (32 - (r))); x1 ^= x0; }
  TF_ROUND(13) TF_ROUND(15) TF_ROUND(26) TF_ROUND(6)
  x0 += k1;  x1 += ks2 + 1u;
  TF_ROUND(17) TF_ROUND(29) TF_ROUND(16) TF_ROUND(24)
  x0 += ks2; x1 += k0 + 2u;
  TF_ROUND(13) TF_ROUND(15) TF_ROUND(26) TF_ROUND(6)
  x0 += k0;  x1 += k1 + 3u;
  TF_ROUND(17) TF_ROUND(29) TF_ROUND(16) TF_ROUND(24)
  x0 += k1;  x1 += ks2 + 4u;
  TF_ROUND(13) TF_ROUND(15) TF_ROUND(26) TF_ROUND(6)
  x0 += ks2; x1 += k0 + 5u;
#undef TF_ROUND
  o0 = x0; o1 = x1;
}

// jax.random uniform [0,1): counter=(0, flat_idx), bits=o0^o1, top-23 into mantissa
__device__ __forceinline__ float tf_u01(uint32_t k0, uint32_t k1, uint32_t idx) {
  uint32_t o0, o1;
  threefry2x32(k0, k1, 0u, idx, o0, o1);
  uint32_t bits = o0 ^ o1;
  uint32_t fb = (bits >> 9) | 0x3F800000u;
  return __uint_as_float(fb) - 1.0f;
}

// ---------------- Stage A0: normalize prototypes ----------------
__global__ void proto_kernel(const float* __restrict__ proto_rgb,
                             const float* __restrict__ proto_dep,
                             float* __restrict__ ph_rgb, float* __restrict__ ph_dep) {
  int b = blockIdx.x, lane = threadIdx.x;  // 8 blocks x 64 threads
  for (int mo = 0; mo < 2; ++mo) {
    const float* src = mo ? proto_dep : proto_rgb;
    float* dst = mo ? ph_dep : ph_rgb;
    float v[4]; float ss = 0.f;
#pragma unroll
    for (int k = 0; k < 4; ++k) { v[k] = src[b * 256 + lane + 64 * k]; ss += v[k] * v[k]; }
#pragma unroll
    for (int off = 32; off > 0; off >>= 1) ss += __shfl_xor(ss, off, 64);
    float nrm = fmaxf(sqrtf(ss), 1e-12f);
#pragma unroll
    for (int k = 0; k < 4; ++k) dst[b * 256 + lane + 64 * k] = v[k] / nrm;
  }
}

// ---------------- Stage A1: cosine-sim maps ----------------
__global__ __launch_bounds__(256) void sim_kernel(
    const float* __restrict__ f_rgb, const float* __restrict__ f_dep,
    const float* __restrict__ ph_rgb, const float* __restrict__ ph_dep,
    float* __restrict__ sim_rgb, float* __restrict__ sim_dep) {
  int tid = threadIdx.x;
  int bm = blockIdx.y;                 // 16: (b, modality)
  int b = bm >> 1, mo = bm & 1;
  const float* f  = mo ? f_dep : f_rgb;
  const float* ph = mo ? ph_dep : ph_rgb;
  float* sim = mo ? sim_dep : sim_rgb;
  __shared__ float shp[256];
  shp[tid] = ph[b * 256 + tid];
  __syncthreads();
  int p = blockIdx.x * 256 + tid;      // position within [4096]
  const float* base = f + (size_t)b * 256 * 4096 + p;
  float dot = 0.f, ss = 0.f;
#pragma unroll 8
  for (int c = 0; c < 256; ++c) {
    float x = base[(size_t)c * 4096];  // coalesced across lanes
    dot += x * shp[c];
    ss  += x * x;
  }
  float fn = fmaxf(sqrtf(ss), 1e-12f);
  sim[b * 4096 + p] = dot / fn;
}

// ---------------- Stage A2: batch-mean maps ----------------
__global__ __launch_bounds__(256) void npmaps_kernel(
    const float* __restrict__ sim_rgb, const float* __restrict__ sim_dep,
    const float* __restrict__ qmask, const float* __restrict__ r_dep,
    float* __restrict__ npm) {
  int i = blockIdx.x * 256 + threadIdx.x;  // 0..4095
  float sr = 0.f, sd = 0.f, sm = 0.f, sq = 0.f;
#pragma unroll
  for (int b = 0; b < 8; ++b) {
    sr += sim_rgb[b * 4096 + i];
    sd += sim_dep[b * 4096 + i];
    sm += qmask[b * 4096 + i];
    sq += r_dep[b * 4096 + i];
  }
  npm[i]          = sr * 0.125f;
  npm[4096 + i]   = sd * 0.125f;
  npm[8192 + i]   = sm * 0.125f;
  npm[12288 + i]  = sq * 0.125f;
}

// ---------------- Stage B: PSO sufficient statistics ----------------
// fused = w0*(m*r) + w1*(m*d) + w2*((1-m)*r) + w3*((1-m)*d) is linear in 4
// basis maps -> fitness needs only S[4]=sums, G[4x4]=Gram, V[4]=dot with mn,
// mn_norm, pen_fg, pen_bg.
__global__ __launch_bounds__(256) void stats_kernel(const float* __restrict__ npm,
                                                    float* __restrict__ stats) {
  const float* np_rgb  = npm;
  const float* np_dep  = npm + 4096;
  const float* np_mask = npm + 8192;
  const float* np_rdep = npm + 12288;
  __shared__ float col[17][257];
  __shared__ float res1[17];
  __shared__ float res2[5];
  int tid = threadIdx.x;
  float acc[17];
#pragma unroll
  for (int k = 0; k < 17; ++k) acc[k] = 0.f;
  for (int i = tid; i < 4096; i += 256) {
    float m = np_mask[i], r = np_rgb[i], d = np_dep[i], q = np_rdep[i];
    float om = 1.f - m;
    float M1 = m * r, M2 = m * d, M3 = om * r, M4 = om * d;
    acc[0] += m;
    acc[1] += M1; acc[2] += M2; acc[3] += M3; acc[4] += M4;
    acc[5] += M1 * M1; acc[6] += M1 * M2; acc[7] += M1 * M3; acc[8] += M1 * M4;
    acc[9] += M2 * M2; acc[10] += M2 * M3; acc[11] += M2 * M4;
    acc[12] += M3 * M3; acc[13] += M3 * M4; acc[14] += M4 * M4;
    float oq = 1.f - q;
    acc[15] += oq * m; acc[16] += oq * om;
  }
#pragma unroll
  for (int k = 0; k < 17; ++k) col[k][tid] = acc[k];
  __syncthreads();
  if (tid < 17) { float s = 0.f; for (int i = 0; i < 256; ++i) s += col[tid][i]; res1[tid] = s; }
  __syncthreads();
  float mask_mean = res1[0] * (1.f / 4096.f);
  float a2[5] = {0.f, 0.f, 0.f, 0.f, 0.f};
  for (int i = tid; i < 4096; i += 256) {
    float m = np_mask[i], r = np_rgb[i], d = np_dep[i];
    float om = 1.f - m;
    float mn = m - mask_mean;
    a2[0] += m * r * mn; a2[1] += m * d * mn;
    a2[2] += om * r * mn; a2[3] += om * d * mn;
    a2[4] += mn * mn;
  }
  __syncthreads();
#pragma unroll
  for (int k = 0; k < 5; ++k) col[k][tid] = a2[k];
  __syncthreads();
  if (tid < 5) { float s = 0.f; for (int i = 0; i < 256; ++i) s += col[tid][i]; res2[tid] = s; }
  __syncthreads();
  if (tid == 0) {
    stats[0] = res1[1]; stats[1] = res1[2]; stats[2] = res1[3]; stats[3] = res1[4];
    float G11 = res1[5], G12 = res1[6], G13 = res1[7], G14 = res1[8];
    float G22 = res1[9], G23 = res1[10], G24 = res1[11];
    float G33 = res1[12], G34 = res1[13], G44 = res1[14];
    float Gf[16] = {G11, G12, G13, G14,  G12, G22, G23, G24,
                    G13, G23, G33, G34,  G14, G24, G34, G44};
    for (int k = 0; k < 16; ++k) stats[4 + k] = Gf[k];
    stats[20] = res2[0]; stats[21] = res2[1]; stats[22] = res2[2]; stats[23] = res2[3];
    stats[24] = sqrtf(res2[4]) + 1e-8f;         // mn_norm (already + EPS)
    stats[25] = res1[15] * (1.f / 4096.f);      // pen_fg
    stats[26] = res1[16] * (1.f / 4096.f);      // pen_bg
  }
}

// ---------------- Stage C: PSO (one wave) ----------------
__device__ __forceinline__ float pso_fitness(const float pos[6],
    const float S[4], const float G[16], const float V[4],
    float mn_norm, float pen_fg, float pen_bg) {
  float e0 = expf(pos[0]), e1 = expf(pos[1]), e2 = expf(pos[2]), e3 = expf(pos[3]);
  float fgs = e0 + e1 + 1e-8f;
  float bgs = e2 + e3 + 1e-8f;
  float w[4] = {e0 / fgs, e1 / fgs, e2 / bgs, e3 / bgs};
  float num = 0.f, mus = 0.f;
#pragma unroll
  for (int k = 0; k < 4; ++k) { num += w[k] * V[k]; mus += w[k] * S[k]; }
  float mu = mus * (1.f / 4096.f);
  float q = 0.f;
#pragma unroll
  for (int j = 0; j < 4; ++j)
#pragma unroll
    for (int k = 0; k < 4; ++k) q += w[j] * G[j * 4 + k] * w[k];
  float fn2 = fmaxf(q - mus * mu, 0.f);   // sum(fn^2) = w'Gw - 4096*mu^2
  float ncc = num / (sqrtf(fn2) * mn_norm + 1e-8f);
  return ncc - 0.3f * (w[1] * pen_fg + w[3] * pen_bg);
}

__global__ void pso_kernel(const float* __restrict__ stats, float* __restrict__ pout) {
  __shared__ float sh_pbfit[30];
  __shared__ float sh_pbpos[30][6];
  __shared__ float sh_gb[7];   // [0..5]=gb_pos, [6]=gb_fit
  int lane = threadIdx.x;      // 64 threads, one wave
  float S[4], G[16], V[4];
#pragma unroll
  for (int k = 0; k < 4; ++k) S[k] = stats[k];
#pragma unroll
  for (int k = 0; k < 16; ++k) G[k] = stats[4 + k];
#pragma unroll
  for (int k = 0; k < 4; ++k) V[k] = stats[20 + k];
  float mn_norm = stats[24], pen_fg = stats[25], pen_bg = stats[26];

  // split(key(42), 4): key_i = cipher((0,42),(0,i))
  uint32_t kp0, kp1, kv0, kv1, ka0, ka1, kb0, kb1;
  threefry2x32(0u, 42u, 0u, 0u, kp0, kp1);
  threefry2x32(0u, 42u, 0u, 1u, kv0, kv1);
  threefry2x32(0u, 42u, 0u, 2u, ka0, ka1);
  threefry2x32(0u, 42u, 0u, 3u, kb0, kb1);

  bool act = lane < 30;
  float pos[6], vel[6], pbp[6];
  float pbf = -3.0e38f;
  if (act) {
#pragma unroll
    for (int d = 0; d < 6; ++d) {
      uint32_t i = (uint32_t)(lane * 6 + d);
      pos[d] = fmaxf(-2.0f, tf_u01(kp0, kp1, i) * 4.0f - 2.0f);
      vel[d] = fmaxf(-0.5f, tf_u01(kv0, kv1, i) - 0.5f);
      pbp[d] = pos[d];
    }
    pbf = pso_fitness(pos, S, G, V, mn_norm, pen_fg, pen_bg);
    sh_pbfit[lane] = pbf;
#pragma unroll
    for (int d = 0; d < 6; ++d) sh_pbpos[lane][d] = pbp[d];
  }
  __syncthreads();
  if (lane == 0) {  // first-max argmax, unconditional init of gb
    int bi = 0; float bf = sh_pbfit[0];
    for (int i = 1; i < 30; ++i) if (sh_pbfit[i] > bf) { bf = sh_pbfit[i]; bi = i; }
    sh_gb[6] = bf;
    for (int d = 0; d < 6; ++d) sh_gb[d] = sh_pbpos[bi][d];
  }
  __syncthreads();

  for (int t = 0; t < 40; ++t) {
    float gb[6];
#pragma unroll
    for (int d = 0; d < 6; ++d) gb[d] = sh_gb[d];
    if (act) {
#pragma unroll
      for (int d = 0; d < 6; ++d) {
        uint32_t i = (uint32_t)(t * 180 + lane * 6 + d);
        float r1 = tf_u01(ka0, ka1, i);
        float r2 = tf_u01(kb0, kb1, i);
        vel[d] = 0.7f * vel[d] + 1.5f * r1 * (pbp[d] - pos[d]) + 1.5f * r2 * (gb[d] - pos[d]);
        pos[d] = fmaxf(-3.0f, fminf(pos[d] + vel[d], 3.0f));
      }
      float f = pso_fitness(pos, S, G, V, mn_norm, pen_fg, pen_bg);
      if (f > pbf) {     // strict, matches `fit > pb_fit`
        pbf = f;
#pragma unroll
        for (int d = 0; d < 6; ++d) pbp[d] = pos[d];
        sh_pbfit[lane] = pbf;
#pragma unroll
        for (int d = 0; d < 6; ++d) sh_pbpos[lane][d] = pbp[d];
      }
    }
    __syncthreads();
    if (lane == 0) {
      int bi = 0; float bf = sh_pbfit[0];
      for (int i = 1; i < 30; ++i) if (sh_pbfit[i] > bf) { bf = sh_pbfit[i]; bi = i; }
      if (bf > sh_gb[6]) {   // strict, matches `improve`
        sh_gb[6] = bf;
        for (int d = 0; d < 6; ++d) sh_gb[d] = sh_pbpos[bi][d];
      }
    }
    __syncthreads();
  }
  if (lane == 0) {
    float e0 = expf(sh_gb[0]), e1 = expf(sh_gb[1]), e2 = expf(sh_gb[2]), e3 = expf(sh_gb[3]);
    float fgs = e0 + e1 + 1e-8f, bgs = e2 + e3 + 1e-8f;
    pout[0] = e0 / fgs;  // rgb_fg
    pout[1] = e1 / fgs;  // dep_fg
    pout[2] = e2 / bgs;  // rgb_bg
    pout[3] = e3 / bgs;  // dep_bg
  }
}

// ---------------- Stage D0: per-position fusion coefficients ----------------
__global__ __launch_bounds__(256) void ab_kernel(
    const float* __restrict__ sim_rgb, const float* __restrict__ sim_dep,
    const float* __restrict__ pout, float2* __restrict__ ab) {
  int i = blockIdx.x * 256 + threadIdx.x;  // 0..32767 (b*4096+p)
  float a = pout[0], bb = pout[1], c = pout[2], d = pout[3];
  float s = sim_rgb[i] + sim_dep[i];
  float pr = 1.f / (1.f + expf(-3.f * s));   // sigmoid(3*(rs+ds))
  float2 r;
  r.x = pr * a + (1.f - pr) * c;   // coefficient on f_rgb
  r.y = pr * bb + (1.f - pr) * d;  // coefficient on f_depth
  ab[i] = r;
}

// ---------------- Stage D1: fused (alpha*f_rgb+beta*f_dep) x W^T + BN + ReLU --
__global__ __launch_bounds__(256) void gemm_kernel(
    const float* __restrict__ f_rgb, const float* __restrict__ f_dep,
    const float2* __restrict__ ab, const float* __restrict__ W,
    const float* __restrict__ bn_g, const float* __restrict__ bn_b,
    const float* __restrict__ bn_m, const float* __restrict__ bn_v,
    float* __restrict__ out) {
  __shared__ float Wt[64][65];
  __shared__ float Ft[64][65];
  int tid = threadIdx.x;
  int pt = blockIdx.x, ot = blockIdx.y, b = blockIdx.z;
  int p0 = pt * 64;
  int tp = tid & 15, to = tid >> 4;     // 4x4 micro-tile coords
  int pp = tid & 63, crow = tid >> 6;   // F staging
  int wcol = tid & 63, wrow = tid >> 6; // W staging
  float2 abv = ab[b * 4096 + p0 + pp];  // per-position coeffs, loaded once
  const float* frb = f_rgb + (size_t)b * 256 * 4096 + p0 + pp;
  const float* fdb = f_dep + (size_t)b * 256 * 4096 + p0 + pp;
  float acc[4][4];
#pragma unroll
  for (int i = 0; i < 4; ++i)
#pragma unroll
    for (int j = 0; j < 4; ++j) acc[i][j] = 0.f;

  for (int c0 = 0; c0 < 256; c0 += 64) {
#pragma unroll
    for (int k = 0; k < 16; ++k) {
      int row = wrow + k * 4;
      Wt[row][wcol] = W[(ot * 64 + row) * 256 + c0 + wcol];
    }
#pragma unroll
    for (int k = 0; k < 16; ++k) {
      int cc = crow + k * 4;
      float xr = frb[(size_t)(c0 + cc) * 4096];
      float xd = fdb[(size_t)(c0 + cc) * 4096];
      Ft[cc][pp] = abv.x * xr + abv.y * xd;  // f_fused built on the fly
    }
    __syncthreads();
#pragma unroll 16
    for (int cc = 0; cc < 64; ++cc) {
      float wv[4], fv[4];
#pragma unroll
      for (int i = 0; i < 4; ++i) wv[i] = Wt[to * 4 + i][cc];
#pragma unroll
      for (int j = 0; j < 4; ++j) fv[j] = Ft[cc][tp * 4 + j];
#pragma unroll
      for (int i = 0; i < 4; ++i)
#pragma unroll
        for (int j = 0; j < 4; ++j) acc[i][j] += wv[i] * fv[j];
    }
    __syncthreads();
  }
#pragma unroll
  for (int i = 0; i < 4; ++i) {
    int o = ot * 64 + to * 4 + i;
    float inv = bn_g[o] / sqrtf(bn_v[o] + 1e-5f);
    float sh = bn_b[o] - bn_m[o] * inv;
    float4 v;
    v.x = fmaxf(acc[i][0] * inv + sh, 0.f);
    v.y = fmaxf(acc[i][1] * inv + sh, 0.f);
    v.z = fmaxf(acc[i][2] * inv + sh, 0.f);
    v.w = fmaxf(acc[i][3] * inv + sh, 0.f);
    *(float4*)(&out[((size_t)(b * 256 + o)) * 4096 + p0 + tp * 4]) = v;
  }
}

extern "C" void kernel_launch(void* const* d_in, const int* in_sizes, int n_in,
                              void* d_out, int out_size, void* d_ws, size_t ws_size,
                              hipStream_t stream) {
  (void)in_sizes; (void)n_in; (void)out_size; (void)ws_size;
  const float* f_rgb     = (const float*)d_in[0];
  const float* f_depth   = (const float*)d_in[1];
  // d_in[2] = r_rgb (unused by reference)
  const float* r_depth   = (const float*)d_in[3];
  const float* proto_rgb = (const float*)d_in[4];
  const float* proto_dep = (const float*)d_in[5];
  const float* qmask     = (const float*)d_in[6];
  const float* conv_w    = (const float*)d_in[7];
  const float* bn_g      = (const float*)d_in[8];
  const float* bn_b      = (const float*)d_in[9];
  const float* bn_m      = (const float*)d_in[10];
  const float* bn_v      = (const float*)d_in[11];
  float* out = (float*)d_out;
  float* ws  = (float*)d_ws;

  float* ph_rgb  = ws + WS_PH_RGB;
  float* ph_dep  = ws + WS_PH_DEP;
  float* sim_rgb = ws + WS_SIM_RGB;
  float* sim_dep = ws + WS_SIM_DEP;
  float* npm     = ws + WS_NPMAPS;
  float* stats   = ws + WS_STATS;
  float* pout    = ws + WS_POUT;
  float2* ab     = (float2*)(ws + WS_AB);

  proto_kernel<<<dim3(8), dim3(64), 0, stream>>>(proto_rgb, proto_dep, ph_rgb, ph_dep);
  sim_kernel<<<dim3(16, 16), dim3(256), 0, stream>>>(f_rgb, f_depth, ph_rgb, ph_dep,
                                                     sim_rgb, sim_dep);
  npmaps_kernel<<<dim3(16), dim3(256), 0, stream>>>(sim_rgb, sim_dep, qmask, r_depth, npm);
  stats_kernel<<<dim3(1), dim3(256), 0, stream>>>(npm, stats);
  pso_kernel<<<dim3(1), dim3(64), 0, stream>>>(stats, pout);
  ab_kernel<<<dim3(128), dim3(256), 0, stream>>>(sim_rgb, sim_dep, pout, ab);
  gemm_kernel<<<dim3(64, 4, 8), dim3(256), 0, stream>>>(f_rgb, f_depth, ab, conv_w,
                                                        bn_g, bn_b, bn_m, bn_v, out);
}

// Round 2
// 190.831 us; speedup vs baseline: 1.2140x; 1.2140x over previous
//
#include <hip/hip_runtime.h>
#include <stdint.h>
#include <float.h>

// Problem geometry: B=8, C=256, H=W=64 (HW=4096). Output [8,256,64,64] f32.
//
// ws layout (float offsets):
static constexpr size_t WS_PH_RGB  = 0;        // [8][256] normalized proto rgb
static constexpr size_t WS_PH_DEP  = 2048;     // [8][256]
static constexpr size_t WS_SIM_RGB = 4096;     // [8][4096]
static constexpr size_t WS_SIM_DEP = 36864;    // [8][4096]
static constexpr size_t WS_NPMAPS  = 69632;    // np maps [4][4096]; reused as RNG buffer after stats_kernel
static constexpr size_t WS_STATS   = 86016;    // 27 floats
static constexpr size_t WS_POUT    = 86048;    // 4 floats
static constexpr size_t WS_AB      = 90112;    // [8][4096] float2

// RNG buffer layout (aliased onto WS_NPMAPS, 14760 <= 16384 floats):
//  [0..180)        init pos draws (transformed), idx = p*6+d
//  [180..360)      init vel draws (transformed)
//  [360 + t*360 + p*12 + j)   j<6: r1[d=j], j>=6: r2[d=j-6]   (raw u01)

// ---------------- JAX threefry2x32 (partitionable semantics) ----------------
__device__ __forceinline__ void threefry2x32(uint32_t k0, uint32_t k1,
                                             uint32_t c0, uint32_t c1,
                                             uint32_t& o0, uint32_t& o1) {
  uint32_t ks2 = k0 ^ k1 ^ 0x1BD11BDAu;
  uint32_t x0 = c0 + k0;
  uint32_t x1 = c1 + k1;
#define TF_ROUND(r) { x0 += x1; x1 = (x1 << (r)) | (x1 >> (32 - (r))); x1 ^= x0; }
  TF_ROUND(13) TF_ROUND(15) TF_ROUND(26) TF_ROUND(6)
  x0 += k1;  x1 += ks2 + 1u;
  TF_ROUND(17) TF_ROUND(29) TF_ROUND(16) TF_ROUND(24)
  x0 += ks2; x1 += k0 + 2u;
  TF_ROUND(13) TF_ROUND(15) TF_ROUND(26) TF_ROUND(6)
  x0 += k0;  x1 += k1 + 3u;
  TF_ROUND(17) TF_ROUND(29) TF_ROUND(16) TF_ROUND(24)
  x0 += k1;  x1 += ks2 + 4u;
  TF_ROUND(13) TF_ROUND(15) TF_ROUND(26) TF_ROUND(6)
  x0 += ks2; x1 += k0 + 5u;
#undef TF_ROUND
  o0 = x0; o1 = x1;
}

__device__ __forceinline__ float tf_u01(uint32_t k0, uint32_t k1, uint32_t idx) {
  uint32_t o0, o1;
  threefry2x32(k0, k1, 0u, idx, o0, o1);
  uint32_t bits = o0 ^ o1;
  uint32_t fb = (bits >> 9) | 0x3F800000u;
  return __uint_as_float(fb) - 1.0f;
}

// ---------------- Stage A0: normalize prototypes ----------------
__global__ void proto_kernel(const float* __restrict__ proto_rgb,
                             const float* __restrict__ proto_dep,
                             float* __restrict__ ph_rgb, float* __restrict__ ph_dep) {
  int b = blockIdx.x, lane = threadIdx.x;  // 8 blocks x 64 threads
  for (int mo = 0; mo < 2; ++mo) {
    const float* src = mo ? proto_dep : proto_rgb;
    float* dst = mo ? ph_dep : ph_rgb;
    float v[4]; float ss = 0.f;
#pragma unroll
    for (int k = 0; k < 4; ++k) { v[k] = src[b * 256 + lane + 64 * k]; ss += v[k] * v[k]; }
#pragma unroll
    for (int off = 32; off > 0; off >>= 1) ss += __shfl_xor(ss, off, 64);
    float nrm = fmaxf(sqrtf(ss), 1e-12f);
#pragma unroll
    for (int k = 0; k < 4; ++k) dst[b * 256 + lane + 64 * k] = v[k] / nrm;
  }
}

// ---------------- Stage A1: cosine-sim maps ----------------
__global__ __launch_bounds__(256) void sim_kernel(
    const float* __restrict__ f_rgb, const float* __restrict__ f_dep,
    const float* __restrict__ ph_rgb, const float* __restrict__ ph_dep,
    float* __restrict__ sim_rgb, float* __restrict__ sim_dep) {
  int tid = threadIdx.x;
  int bm = blockIdx.y;                 // 16: (b, modality)
  int b = bm >> 1, mo = bm & 1;
  const float* f  = mo ? f_dep : f_rgb;
  const float* ph = mo ? ph_dep : ph_rgb;
  float* sim = mo ? sim_dep : sim_rgb;
  __shared__ float shp[256];
  shp[tid] = ph[b * 256 + tid];
  __syncthreads();
  int p = blockIdx.x * 256 + tid;      // position within [4096]
  const float* base = f + (size_t)b * 256 * 4096 + p;
  float dot = 0.f, ss = 0.f;
#pragma unroll 8
  for (int c = 0; c < 256; ++c) {
    float x = base[(size_t)c * 4096];  // coalesced across lanes
    dot += x * shp[c];
    ss  += x * x;
  }
  float fn = fmaxf(sqrtf(ss), 1e-12f);
  sim[b * 4096 + p] = dot / fn;
}

// ---------------- Stage A2: batch-mean maps ----------------
__global__ __launch_bounds__(256) void npmaps_kernel(
    const float* __restrict__ sim_rgb, const float* __restrict__ sim_dep,
    const float* __restrict__ qmask, const float* __restrict__ r_dep,
    float* __restrict__ npm) {
  int i = blockIdx.x * 256 + threadIdx.x;  // 0..4095
  float sr = 0.f, sd = 0.f, sm = 0.f, sq = 0.f;
#pragma unroll
  for (int b = 0; b < 8; ++b) {
    sr += sim_rgb[b * 4096 + i];
    sd += sim_dep[b * 4096 + i];
    sm += qmask[b * 4096 + i];
    sq += r_dep[b * 4096 + i];
  }
  npm[i]          = sr * 0.125f;
  npm[4096 + i]   = sd * 0.125f;
  npm[8192 + i]   = sm * 0.125f;
  npm[12288 + i]  = sq * 0.125f;
}

// ---------------- Stage B: PSO sufficient statistics ----------------
__global__ __launch_bounds__(256) void stats_kernel(const float* __restrict__ npm,
                                                    float* __restrict__ stats) {
  const float* np_rgb  = npm;
  const float* np_dep  = npm + 4096;
  const float* np_mask = npm + 8192;
  const float* np_rdep = npm + 12288;
  __shared__ float col[17][257];
  __shared__ float res1[17];
  __shared__ float res2[5];
  int tid = threadIdx.x;
  float acc[17];
#pragma unroll
  for (int k = 0; k < 17; ++k) acc[k] = 0.f;
  for (int i = tid; i < 4096; i += 256) {
    float m = np_mask[i], r = np_rgb[i], d = np_dep[i], q = np_rdep[i];
    float om = 1.f - m;
    float M1 = m * r, M2 = m * d, M3 = om * r, M4 = om * d;
    acc[0] += m;
    acc[1] += M1; acc[2] += M2; acc[3] += M3; acc[4] += M4;
    acc[5] += M1 * M1; acc[6] += M1 * M2; acc[7] += M1 * M3; acc[8] += M1 * M4;
    acc[9] += M2 * M2; acc[10] += M2 * M3; acc[11] += M2 * M4;
    acc[12] += M3 * M3; acc[13] += M3 * M4; acc[14] += M4 * M4;
    float oq = 1.f - q;
    acc[15] += oq * m; acc[16] += oq * om;
  }
#pragma unroll
  for (int k = 0; k < 17; ++k) col[k][tid] = acc[k];
  __syncthreads();
  if (tid < 17) { float s = 0.f; for (int i = 0; i < 256; ++i) s += col[tid][i]; res1[tid] = s; }
  __syncthreads();
  float mask_mean = res1[0] * (1.f / 4096.f);
  float a2[5] = {0.f, 0.f, 0.f, 0.f, 0.f};
  for (int i = tid; i < 4096; i += 256) {
    float m = np_mask[i], r = np_rgb[i], d = np_dep[i];
    float om = 1.f - m;
    float mn = m - mask_mean;
    a2[0] += m * r * mn; a2[1] += m * d * mn;
    a2[2] += om * r * mn; a2[3] += om * d * mn;
    a2[4] += mn * mn;
  }
  __syncthreads();
#pragma unroll
  for (int k = 0; k < 5; ++k) col[k][tid] = a2[k];
  __syncthreads();
  if (tid < 5) { float s = 0.f; for (int i = 0; i < 256; ++i) s += col[tid][i]; res2[tid] = s; }
  __syncthreads();
  if (tid == 0) {
    stats[0] = res1[1]; stats[1] = res1[2]; stats[2] = res1[3]; stats[3] = res1[4];
    float G11 = res1[5], G12 = res1[6], G13 = res1[7], G14 = res1[8];
    float G22 = res1[9], G23 = res1[10], G24 = res1[11];
    float G33 = res1[12], G34 = res1[13], G44 = res1[14];
    float Gf[16] = {G11, G12, G13, G14,  G12, G22, G23, G24,
                    G13, G23, G33, G34,  G14, G24, G34, G44};
    for (int k = 0; k < 16; ++k) stats[4 + k] = Gf[k];
    stats[20] = res2[0]; stats[21] = res2[1]; stats[22] = res2[2]; stats[23] = res2[3];
    stats[24] = sqrtf(res2[4]) + 1e-8f;         // mn_norm (already + EPS)
    stats[25] = res1[15] * (1.f / 4096.f);      // pen_fg
    stats[26] = res1[16] * (1.f / 4096.f);      // pen_bg
  }
}

// ---------------- Stage B2: all PSO randoms, fully parallel ----------------
// 14760 draws: 180 pos + 180 vel + 40*180 r1 + 40*180 r2. One thread per draw.
__global__ __launch_bounds__(256) void rng_kernel(float* __restrict__ rng) {
  int g = blockIdx.x * 256 + threadIdx.x;
  if (g >= 14760) return;
  int kind; uint32_t splitIdx, ctr, dst;
  if (g < 180) {
    kind = 0; splitIdx = 0; ctr = (uint32_t)g; dst = (uint32_t)g;
  } else if (g < 360) {
    kind = 1; splitIdx = 1; ctr = (uint32_t)(g - 180); dst = (uint32_t)g;
  } else if (g < 7560) {
    uint32_t c = (uint32_t)(g - 360);
    kind = 2; splitIdx = 2; ctr = c;
    uint32_t t = c / 180u, rem = c % 180u, p = rem / 6u, d = rem % 6u;
    dst = 360u + t * 360u + p * 12u + d;
  } else {
    uint32_t c = (uint32_t)(g - 7560);
    kind = 3; splitIdx = 3; ctr = c;
    uint32_t t = c / 180u, rem = c % 180u, p = rem / 6u, d = rem % 6u;
    dst = 360u + t * 360u + p * 12u + 6u + d;
  }
  uint32_t k0, k1;
  threefry2x32(0u, 42u, 0u, splitIdx, k0, k1);   // jax.random.split
  float u = tf_u01(k0, k1, ctr);
  float v;
  if (kind == 0)      v = fmaxf(-2.0f, u * 4.0f - 2.0f);   // uniform(-2,2)
  else if (kind == 1) v = fmaxf(-0.5f, u - 0.5f);          // uniform(-0.5,0.5)
  else                v = u;
  rng[dst] = v;
}

// ---------------- Stage C: PSO (one wave, register+shuffle only) ----------------
__device__ __forceinline__ float pso_fitness(const float pos[6],
    const float S[4], const float G[16], const float V[4],
    float mn_norm, float pen_fg, float pen_bg) {
  float e0 = expf(pos[0]), e1 = expf(pos[1]), e2 = expf(pos[2]), e3 = expf(pos[3]);
  float fgs = e0 + e1 + 1e-8f;
  float bgs = e2 + e3 + 1e-8f;
  float w[4] = {e0 / fgs, e1 / fgs, e2 / bgs, e3 / bgs};
  float num = 0.f, mus = 0.f;
#pragma unroll
  for (int k = 0; k < 4; ++k) { num += w[k] * V[k]; mus += w[k] * S[k]; }
  float mu = mus * (1.f / 4096.f);
  float q = 0.f;
#pragma unroll
  for (int j = 0; j < 4; ++j)
#pragma unroll
    for (int k = 0; k < 4; ++k) q += w[j] * G[j * 4 + k] * w[k];
  float fn2 = fmaxf(q - mus * mu, 0.f);   // sum(fn^2) = w'Gw - 4096*mu^2
  float ncc = num / (sqrtf(fn2) * mn_norm + 1e-8f);
  return ncc - 0.3f * (w[1] * pen_fg + w[3] * pen_bg);
}

// butterfly argmax over 64 lanes; ties -> lowest lane (matches jnp.argmax)
__device__ __forceinline__ void argmax64(float& bf, int& bl) {
#pragma unroll
  for (int off = 32; off > 0; off >>= 1) {
    float of = __shfl_xor(bf, off, 64);
    int   ol = __shfl_xor(bl, off, 64);
    if (of > bf || (of == bf && ol < bl)) { bf = of; bl = ol; }
  }
}

__global__ void pso_kernel(const float* __restrict__ stats,
                           const float* __restrict__ rng,
                           float* __restrict__ pout) {
  int lane = threadIdx.x;          // 64 threads = 1 wave
  bool act = lane < 30;
  float S[4], G[16], V[4];
#pragma unroll
  for (int k = 0; k < 4; ++k) S[k] = stats[k];
#pragma unroll
  for (int k = 0; k < 16; ++k) G[k] = stats[4 + k];
#pragma unroll
  for (int k = 0; k < 4; ++k) V[k] = stats[20 + k];
  float mn_norm = stats[24], pen_fg = stats[25], pen_bg = stats[26];

  float pos[6], vel[6], pbp[6];
#pragma unroll
  for (int d = 0; d < 6; ++d) { pos[d] = 0.f; vel[d] = 0.f; }
  if (act) {
#pragma unroll
    for (int d = 0; d < 6; ++d) {
      pos[d] = rng[lane * 6 + d];
      vel[d] = rng[180 + lane * 6 + d];
    }
  }
#pragma unroll
  for (int d = 0; d < 6; ++d) pbp[d] = pos[d];

  float f0 = pso_fitness(pos, S, G, V, mn_norm, pen_fg, pen_bg);
  float pbf = act ? f0 : -FLT_MAX;

  // init global best
  float cf = pbf; int cl = lane;
  argmax64(cf, cl);
  float gbf = cf;
  float gb[6];
#pragma unroll
  for (int d = 0; d < 6; ++d) gb[d] = __shfl(pbp[d], cl, 64);

  const float* rbase = rng + 360;
  float4 rA, rB, rC;
  rA = rB = rC = make_float4(0.f, 0.f, 0.f, 0.f);
  if (act) {
    const float4* rp = (const float4*)(rbase + lane * 12);
    rA = rp[0]; rB = rp[1]; rC = rp[2];
  }

  for (int t = 0; t < 40; ++t) {
    float r1[6] = {rA.x, rA.y, rA.z, rA.w, rB.x, rB.y};
    float r2[6] = {rB.z, rB.w, rC.x, rC.y, rC.z, rC.w};
    if (t < 39 && act) {              // prefetch next iteration's randoms
      const float4* rp = (const float4*)(rbase + (t + 1) * 360 + lane * 12);
      rA = rp[0]; rB = rp[1]; rC = rp[2];
    }
#pragma unroll
    for (int d = 0; d < 6; ++d) {
      vel[d] = 0.7f * vel[d] + 1.5f * r1[d] * (pbp[d] - pos[d]) + 1.5f * r2[d] * (gb[d] - pos[d]);
      pos[d] = fmaxf(-3.0f, fminf(pos[d] + vel[d], 3.0f));
    }
    float f = pso_fitness(pos, S, G, V, mn_norm, pen_fg, pen_bg);
    if (act && f > pbf) {             // strict, matches `fit > pb_fit`
      pbf = f;
#pragma unroll
      for (int d = 0; d < 6; ++d) pbp[d] = pos[d];
    }
    float bf = pbf; int bl = lane;
    argmax64(bf, bl);                 // uniform result across wave
    if (bf > gbf) {                   // wave-uniform branch; strict `improve`
      gbf = bf;
#pragma unroll
      for (int d = 0; d < 6; ++d) gb[d] = __shfl(pbp[d], bl, 64);
    }
  }

  if (lane == 0) {
    float e0 = expf(gb[0]), e1 = expf(gb[1]), e2 = expf(gb[2]), e3 = expf(gb[3]);
    float fgs = e0 + e1 + 1e-8f, bgs = e2 + e3 + 1e-8f;
    pout[0] = e0 / fgs;  // rgb_fg
    pout[1] = e1 / fgs;  // dep_fg
    pout[2] = e2 / bgs;  // rgb_bg
    pout[3] = e3 / bgs;  // dep_bg
  }
}

// ---------------- Stage D0: per-position fusion coefficients ----------------
__global__ __launch_bounds__(256) void ab_kernel(
    const float* __restrict__ sim_rgb, const float* __restrict__ sim_dep,
    const float* __restrict__ pout, float2* __restrict__ ab) {
  int i = blockIdx.x * 256 + threadIdx.x;  // 0..32767 (b*4096+p)
  float a = pout[0], bb = pout[1], c = pout[2], d = pout[3];
  float s = sim_rgb[i] + sim_dep[i];
  float pr = 1.f / (1.f + expf(-3.f * s));   // sigmoid(3*(rs+ds))
  float2 r;
  r.x = pr * a + (1.f - pr) * c;   // coefficient on f_rgb
  r.y = pr * bb + (1.f - pr) * d;  // coefficient on f_depth
  ab[i] = r;
}

// ---------------- Stage D1: fused (alpha*f_rgb+beta*f_dep) x W^T + BN + ReLU --
__global__ __launch_bounds__(256) void gemm_kernel(
    const float* __restrict__ f_rgb, const float* __restrict__ f_dep,
    const float2* __restrict__ ab, const float* __restrict__ W,
    const float* __restrict__ bn_g, const float* __restrict__ bn_b,
    const float* __restrict__ bn_m, const float* __restrict__ bn_v,
    float* __restrict__ out) {
  __shared__ float Wt[64][65];
  __shared__ float Ft[64][65];
  int tid = threadIdx.x;
  int pt = blockIdx.x, ot = blockIdx.y, b = blockIdx.z;
  int p0 = pt * 64;
  int tp = tid & 15, to = tid >> 4;     // 4x4 micro-tile coords
  int pp = tid & 63, crow = tid >> 6;   // F staging
  int wcol = tid & 63, wrow = tid >> 6; // W staging
  float2 abv = ab[b * 4096 + p0 + pp];  // per-position coeffs, loaded once
  const float* frb = f_rgb + (size_t)b * 256 * 4096 + p0 + pp;
  const float* fdb = f_dep + (size_t)b * 256 * 4096 + p0 + pp;
  float acc[4][4];
#pragma unroll
  for (int i = 0; i < 4; ++i)
#pragma unroll
    for (int j = 0; j < 4; ++j) acc[i][j] = 0.f;

  for (int c0 = 0; c0 < 256; c0 += 64) {
#pragma unroll
    for (int k = 0; k < 16; ++k) {
      int row = wrow + k * 4;
      Wt[row][wcol] = W[(ot * 64 + row) * 256 + c0 + wcol];
    }
#pragma unroll
    for (int k = 0; k < 16; ++k) {
      int cc = crow + k * 4;
      float xr = frb[(size_t)(c0 + cc) * 4096];
      float xd = fdb[(size_t)(c0 + cc) * 4096];
      Ft[cc][pp] = abv.x * xr + abv.y * xd;  // f_fused built on the fly
    }
    __syncthreads();
#pragma unroll 16
    for (int cc = 0; cc < 64; ++cc) {
      float wv[4], fv[4];
#pragma unroll
      for (int i = 0; i < 4; ++i) wv[i] = Wt[to * 4 + i][cc];
#pragma unroll
      for (int j = 0; j < 4; ++j) fv[j] = Ft[cc][tp * 4 + j];
#pragma unroll
      for (int i = 0; i < 4; ++i)
#pragma unroll
        for (int j = 0; j < 4; ++j) acc[i][j] += wv[i] * fv[j];
    }
    __syncthreads();
  }
#pragma unroll
  for (int i = 0; i < 4; ++i) {
    int o = ot * 64 + to * 4 + i;
    float inv = bn_g[o] / sqrtf(bn_v[o] + 1e-5f);
    float sh = bn_b[o] - bn_m[o] * inv;
    float4 v;
    v.x = fmaxf(acc[i][0] * inv + sh, 0.f);
    v.y = fmaxf(acc[i][1] * inv + sh, 0.f);
    v.z = fmaxf(acc[i][2] * inv + sh, 0.f);
    v.w = fmaxf(acc[i][3] * inv + sh, 0.f);
    *(float4*)(&out[((size_t)(b * 256 + o)) * 4096 + p0 + tp * 4]) = v;
  }
}

extern "C" void kernel_launch(void* const* d_in, const int* in_sizes, int n_in,
                              void* d_out, int out_size, void* d_ws, size_t ws_size,
                              hipStream_t stream) {
  (void)in_sizes; (void)n_in; (void)out_size; (void)ws_size;
  const float* f_rgb     = (const float*)d_in[0];
  const float* f_depth   = (const float*)d_in[1];
  // d_in[2] = r_rgb (unused by reference)
  const float* r_depth   = (const float*)d_in[3];
  const float* proto_rgb = (const float*)d_in[4];
  const float* proto_dep = (const float*)d_in[5];
  const float* qmask     = (const float*)d_in[6];
  const float* conv_w    = (const float*)d_in[7];
  const float* bn_g      = (const float*)d_in[8];
  const float* bn_b      = (const float*)d_in[9];
  const float* bn_m      = (const float*)d_in[10];
  const float* bn_v      = (const float*)d_in[11];
  float* out = (float*)d_out;
  float* ws  = (float*)d_ws;

  float* ph_rgb  = ws + WS_PH_RGB;
  float* ph_dep  = ws + WS_PH_DEP;
  float* sim_rgb = ws + WS_SIM_RGB;
  float* sim_dep = ws + WS_SIM_DEP;
  float* npm     = ws + WS_NPMAPS;   // also the RNG buffer after stats_kernel
  float* stats   = ws + WS_STATS;
  float* pout    = ws + WS_POUT;
  float2* ab     = (float2*)(ws + WS_AB);

  proto_kernel<<<dim3(8), dim3(64), 0, stream>>>(proto_rgb, proto_dep, ph_rgb, ph_dep);
  sim_kernel<<<dim3(16, 16), dim3(256), 0, stream>>>(f_rgb, f_depth, ph_rgb, ph_dep,
                                                     sim_rgb, sim_dep);
  npmaps_kernel<<<dim3(16), dim3(256), 0, stream>>>(sim_rgb, sim_dep, qmask, r_depth, npm);
  stats_kernel<<<dim3(1), dim3(256), 0, stream>>>(npm, stats);
  // npm region is dead now -> reuse as RNG buffer (stream order guarantees safety)
  rng_kernel<<<dim3(58), dim3(256), 0, stream>>>(npm);
  pso_kernel<<<dim3(1), dim3(64), 0, stream>>>(stats, npm, pout);
  ab_kernel<<<dim3(128), dim3(256), 0, stream>>>(sim_rgb, sim_dep, pout, ab);
  gemm_kernel<<<dim3(64, 4, 8), dim3(256), 0, stream>>>(f_rgb, f_depth, ab, conv_w,
                                                        bn_g, bn_b, bn_m, bn_v, out);
}

// Round 3
// 137.648 us; speedup vs baseline: 1.6830x; 1.3864x over previous
//
#include <hip/hip_runtime.h>
#include <stdint.h>
#include <float.h>

// Problem geometry: B=8, C=256, H=W=64 (HW=4096). Output [8,256,64,64] f32.
//
// ws layout (float offsets):
static constexpr size_t WS_PH_RGB  = 0;        // [8][256] normalized proto rgb
static constexpr size_t WS_PH_DEP  = 2048;     // [8][256]
static constexpr size_t WS_SIM_RGB = 4096;     // [8][4096]
static constexpr size_t WS_SIM_DEP = 36864;    // [8][4096]
static constexpr size_t WS_NPMAPS  = 69632;    // np maps [4][4096]; reused as RNG buffer after stats_kernel
static constexpr size_t WS_STATS   = 86016;    // 27 floats
static constexpr size_t WS_POUT    = 86048;    // 4 floats
static constexpr size_t WS_AB      = 90112;    // [8][4096] float2 (alpha,beta per position)

typedef short short8 __attribute__((ext_vector_type(8)));
typedef float f32x4 __attribute__((ext_vector_type(4)));

// pack two f32 -> two bf16 (RNE) in one u32 (lo = first element)
__device__ __forceinline__ uint32_t pack_bf2(float a, float b) {
  uint32_t ua = __float_as_uint(a), ub = __float_as_uint(b);
  uint32_t ra = (ua + 0x7fffu + ((ua >> 16) & 1u)) >> 16;
  uint32_t rb = (ub + 0x7fffu + ((ub >> 16) & 1u)) >> 16;
  return (ra & 0xffffu) | (rb << 16);
}

// ---------------- JAX threefry2x32 (partitionable semantics) ----------------
__device__ __forceinline__ void threefry2x32(uint32_t k0, uint32_t k1,
                                             uint32_t c0, uint32_t c1,
                                             uint32_t& o0, uint32_t& o1) {
  uint32_t ks2 = k0 ^ k1 ^ 0x1BD11BDAu;
  uint32_t x0 = c0 + k0;
  uint32_t x1 = c1 + k1;
#define TF_ROUND(r) { x0 += x1; x1 = (x1 << (r)) | (x1 >> (32 - (r))); x1 ^= x0; }
  TF_ROUND(13) TF_ROUND(15) TF_ROUND(26) TF_ROUND(6)
  x0 += k1;  x1 += ks2 + 1u;
  TF_ROUND(17) TF_ROUND(29) TF_ROUND(16) TF_ROUND(24)
  x0 += ks2; x1 += k0 + 2u;
  TF_ROUND(13) TF_ROUND(15) TF_ROUND(26) TF_ROUND(6)
  x0 += k0;  x1 += k1 + 3u;
  TF_ROUND(17) TF_ROUND(29) TF_ROUND(16) TF_ROUND(24)
  x0 += k1;  x1 += ks2 + 4u;
  TF_ROUND(13) TF_ROUND(15) TF_ROUND(26) TF_ROUND(6)
  x0 += ks2; x1 += k0 + 5u;
#undef TF_ROUND
  o0 = x0; o1 = x1;
}

__device__ __forceinline__ float tf_u01(uint32_t k0, uint32_t k1, uint32_t idx) {
  uint32_t o0, o1;
  threefry2x32(k0, k1, 0u, idx, o0, o1);
  uint32_t bits = o0 ^ o1;
  uint32_t fb = (bits >> 9) | 0x3F800000u;
  return __uint_as_float(fb) - 1.0f;
}

// ---------------- Stage A0: normalize prototypes ----------------
__global__ void proto_kernel(const float* __restrict__ proto_rgb,
                             const float* __restrict__ proto_dep,
                             float* __restrict__ ph_rgb, float* __restrict__ ph_dep) {
  int b = blockIdx.x, lane = threadIdx.x;  // 8 blocks x 64 threads
  for (int mo = 0; mo < 2; ++mo) {
    const float* src = mo ? proto_dep : proto_rgb;
    float* dst = mo ? ph_dep : ph_rgb;
    float v[4]; float ss = 0.f;
#pragma unroll
    for (int k = 0; k < 4; ++k) { v[k] = src[b * 256 + lane + 64 * k]; ss += v[k] * v[k]; }
#pragma unroll
    for (int off = 32; off > 0; off >>= 1) ss += __shfl_xor(ss, off, 64);
    float nrm = fmaxf(sqrtf(ss), 1e-12f);
#pragma unroll
    for (int k = 0; k < 4; ++k) dst[b * 256 + lane + 64 * k] = v[k] / nrm;
  }
}

// ---------------- Stage A1: cosine-sim maps ----------------
__global__ __launch_bounds__(256) void sim_kernel(
    const float* __restrict__ f_rgb, const float* __restrict__ f_dep,
    const float* __restrict__ ph_rgb, const float* __restrict__ ph_dep,
    float* __restrict__ sim_rgb, float* __restrict__ sim_dep) {
  int tid = threadIdx.x;
  int bm = blockIdx.y;                 // 16: (b, modality)
  int b = bm >> 1, mo = bm & 1;
  const float* f  = mo ? f_dep : f_rgb;
  const float* ph = mo ? ph_dep : ph_rgb;
  float* sim = mo ? sim_dep : sim_rgb;
  __shared__ float shp[256];
  shp[tid] = ph[b * 256 + tid];
  __syncthreads();
  int p = blockIdx.x * 256 + tid;      // position within [4096]
  const float* base = f + (size_t)b * 256 * 4096 + p;
  float dot = 0.f, ss = 0.f;
#pragma unroll 8
  for (int c = 0; c < 256; ++c) {
    float x = base[(size_t)c * 4096];  // coalesced across lanes
    dot += x * shp[c];
    ss  += x * x;
  }
  float fn = fmaxf(sqrtf(ss), 1e-12f);
  sim[b * 4096 + p] = dot / fn;
}

// ---------------- Stage A2: batch-mean maps ----------------
__global__ __launch_bounds__(256) void npmaps_kernel(
    const float* __restrict__ sim_rgb, const float* __restrict__ sim_dep,
    const float* __restrict__ qmask, const float* __restrict__ r_dep,
    float* __restrict__ npm) {
  int i = blockIdx.x * 256 + threadIdx.x;  // 0..4095
  float sr = 0.f, sd = 0.f, sm = 0.f, sq = 0.f;
#pragma unroll
  for (int b = 0; b < 8; ++b) {
    sr += sim_rgb[b * 4096 + i];
    sd += sim_dep[b * 4096 + i];
    sm += qmask[b * 4096 + i];
    sq += r_dep[b * 4096 + i];
  }
  npm[i]          = sr * 0.125f;
  npm[4096 + i]   = sd * 0.125f;
  npm[8192 + i]   = sm * 0.125f;
  npm[12288 + i]  = sq * 0.125f;
}

// ---------------- Stage B: PSO sufficient statistics ----------------
__global__ __launch_bounds__(256) void stats_kernel(const float* __restrict__ npm,
                                                    float* __restrict__ stats) {
  const float* np_rgb  = npm;
  const float* np_dep  = npm + 4096;
  const float* np_mask = npm + 8192;
  const float* np_rdep = npm + 12288;
  __shared__ float col[17][257];
  __shared__ float res1[17];
  __shared__ float res2[5];
  int tid = threadIdx.x;
  float acc[17];
#pragma unroll
  for (int k = 0; k < 17; ++k) acc[k] = 0.f;
  for (int i = tid; i < 4096; i += 256) {
    float m = np_mask[i], r = np_rgb[i], d = np_dep[i], q = np_rdep[i];
    float om = 1.f - m;
    float M1 = m * r, M2 = m * d, M3 = om * r, M4 = om * d;
    acc[0] += m;
    acc[1] += M1; acc[2] += M2; acc[3] += M3; acc[4] += M4;
    acc[5] += M1 * M1; acc[6] += M1 * M2; acc[7] += M1 * M3; acc[8] += M1 * M4;
    acc[9] += M2 * M2; acc[10] += M2 * M3; acc[11] += M2 * M4;
    acc[12] += M3 * M3; acc[13] += M3 * M4; acc[14] += M4 * M4;
    float oq = 1.f - q;
    acc[15] += oq * m; acc[16] += oq * om;
  }
#pragma unroll
  for (int k = 0; k < 17; ++k) col[k][tid] = acc[k];
  __syncthreads();
  if (tid < 17) { float s = 0.f; for (int i = 0; i < 256; ++i) s += col[tid][i]; res1[tid] = s; }
  __syncthreads();
  float mask_mean = res1[0] * (1.f / 4096.f);
  float a2[5] = {0.f, 0.f, 0.f, 0.f, 0.f};
  for (int i = tid; i < 4096; i += 256) {
    float m = np_mask[i], r = np_rgb[i], d = np_dep[i];
    float om = 1.f - m;
    float mn = m - mask_mean;
    a2[0] += m * r * mn; a2[1] += m * d * mn;
    a2[2] += om * r * mn; a2[3] += om * d * mn;
    a2[4] += mn * mn;
  }
  __syncthreads();
#pragma unroll
  for (int k = 0; k < 5; ++k) col[k][tid] = a2[k];
  __syncthreads();
  if (tid < 5) { float s = 0.f; for (int i = 0; i < 256; ++i) s += col[tid][i]; res2[tid] = s; }
  __syncthreads();
  if (tid == 0) {
    stats[0] = res1[1]; stats[1] = res1[2]; stats[2] = res1[3]; stats[3] = res1[4];
    float G11 = res1[5], G12 = res1[6], G13 = res1[7], G14 = res1[8];
    float G22 = res1[9], G23 = res1[10], G24 = res1[11];
    float G33 = res1[12], G34 = res1[13], G44 = res1[14];
    float Gf[16] = {G11, G12, G13, G14,  G12, G22, G23, G24,
                    G13, G23, G33, G34,  G14, G24, G34, G44};
    for (int k = 0; k < 16; ++k) stats[4 + k] = Gf[k];
    stats[20] = res2[0]; stats[21] = res2[1]; stats[22] = res2[2]; stats[23] = res2[3];
    stats[24] = sqrtf(res2[4]) + 1e-8f;         // mn_norm (already + EPS)
    stats[25] = res1[15] * (1.f / 4096.f);      // pen_fg
    stats[26] = res1[16] * (1.f / 4096.f);      // pen_bg
  }
}

// ---------------- Stage B2: all PSO randoms, fully parallel ----------------
__global__ __launch_bounds__(256) void rng_kernel(float* __restrict__ rng) {
  int g = blockIdx.x * 256 + threadIdx.x;
  if (g >= 14760) return;
  int kind; uint32_t splitIdx, ctr, dst;
  if (g < 180) {
    kind = 0; splitIdx = 0; ctr = (uint32_t)g; dst = (uint32_t)g;
  } else if (g < 360) {
    kind = 1; splitIdx = 1; ctr = (uint32_t)(g - 180); dst = (uint32_t)g;
  } else if (g < 7560) {
    uint32_t c = (uint32_t)(g - 360);
    kind = 2; splitIdx = 2; ctr = c;
    uint32_t t = c / 180u, rem = c % 180u, p = rem / 6u, d = rem % 6u;
    dst = 360u + t * 360u + p * 12u + d;
  } else {
    uint32_t c = (uint32_t)(g - 7560);
    kind = 3; splitIdx = 3; ctr = c;
    uint32_t t = c / 180u, rem = c % 180u, p = rem / 6u, d = rem % 6u;
    dst = 360u + t * 360u + p * 12u + 6u + d;
  }
  uint32_t k0, k1;
  threefry2x32(0u, 42u, 0u, splitIdx, k0, k1);   // jax.random.split
  float u = tf_u01(k0, k1, ctr);
  float v;
  if (kind == 0)      v = fmaxf(-2.0f, u * 4.0f - 2.0f);   // uniform(-2,2)
  else if (kind == 1) v = fmaxf(-0.5f, u - 0.5f);          // uniform(-0.5,0.5)
  else                v = u;
  rng[dst] = v;
}

// ---------------- Stage C: PSO (one wave, register+shuffle only) ----------------
__device__ __forceinline__ float pso_fitness(const float pos[6],
    const float S[4], const float G[16], const float V[4],
    float mn_norm, float pen_fg, float pen_bg) {
  float e0 = expf(pos[0]), e1 = expf(pos[1]), e2 = expf(pos[2]), e3 = expf(pos[3]);
  float fgs = e0 + e1 + 1e-8f;
  float bgs = e2 + e3 + 1e-8f;
  float w[4] = {e0 / fgs, e1 / fgs, e2 / bgs, e3 / bgs};
  float num = 0.f, mus = 0.f;
#pragma unroll
  for (int k = 0; k < 4; ++k) { num += w[k] * V[k]; mus += w[k] * S[k]; }
  float mu = mus * (1.f / 4096.f);
  float q = 0.f;
#pragma unroll
  for (int j = 0; j < 4; ++j)
#pragma unroll
    for (int k = 0; k < 4; ++k) q += w[j] * G[j * 4 + k] * w[k];
  float fn2 = fmaxf(q - mus * mu, 0.f);   // sum(fn^2) = w'Gw - 4096*mu^2
  float ncc = num / (sqrtf(fn2) * mn_norm + 1e-8f);
  return ncc - 0.3f * (w[1] * pen_fg + w[3] * pen_bg);
}

__device__ __forceinline__ void argmax64(float& bf, int& bl) {
#pragma unroll
  for (int off = 32; off > 0; off >>= 1) {
    float of = __shfl_xor(bf, off, 64);
    int   ol = __shfl_xor(bl, off, 64);
    if (of > bf || (of == bf && ol < bl)) { bf = of; bl = ol; }
  }
}

__global__ void pso_kernel(const float* __restrict__ stats,
                           const float* __restrict__ rng,
                           float* __restrict__ pout) {
  int lane = threadIdx.x;          // 64 threads = 1 wave
  bool act = lane < 30;
  float S[4], G[16], V[4];
#pragma unroll
  for (int k = 0; k < 4; ++k) S[k] = stats[k];
#pragma unroll
  for (int k = 0; k < 16; ++k) G[k] = stats[4 + k];
#pragma unroll
  for (int k = 0; k < 4; ++k) V[k] = stats[20 + k];
  float mn_norm = stats[24], pen_fg = stats[25], pen_bg = stats[26];

  float pos[6], vel[6], pbp[6];
#pragma unroll
  for (int d = 0; d < 6; ++d) { pos[d] = 0.f; vel[d] = 0.f; }
  if (act) {
#pragma unroll
    for (int d = 0; d < 6; ++d) {
      pos[d] = rng[lane * 6 + d];
      vel[d] = rng[180 + lane * 6 + d];
    }
  }
#pragma unroll
  for (int d = 0; d < 6; ++d) pbp[d] = pos[d];

  float f0 = pso_fitness(pos, S, G, V, mn_norm, pen_fg, pen_bg);
  float pbf = act ? f0 : -FLT_MAX;

  float cf = pbf; int cl = lane;
  argmax64(cf, cl);
  float gbf = cf;
  float gb[6];
#pragma unroll
  for (int d = 0; d < 6; ++d) gb[d] = __shfl(pbp[d], cl, 64);

  const float* rbase = rng + 360;
  float4 rA, rB, rC;
  rA = rB = rC = make_float4(0.f, 0.f, 0.f, 0.f);
  if (act) {
    const float4* rp = (const float4*)(rbase + lane * 12);
    rA = rp[0]; rB = rp[1]; rC = rp[2];
  }

  for (int t = 0; t < 40; ++t) {
    float r1[6] = {rA.x, rA.y, rA.z, rA.w, rB.x, rB.y};
    float r2[6] = {rB.z, rB.w, rC.x, rC.y, rC.z, rC.w};
    if (t < 39 && act) {              // prefetch next iteration's randoms
      const float4* rp = (const float4*)(rbase + (t + 1) * 360 + lane * 12);
      rA = rp[0]; rB = rp[1]; rC = rp[2];
    }
#pragma unroll
    for (int d = 0; d < 6; ++d) {
      vel[d] = 0.7f * vel[d] + 1.5f * r1[d] * (pbp[d] - pos[d]) + 1.5f * r2[d] * (gb[d] - pos[d]);
      pos[d] = fmaxf(-3.0f, fminf(pos[d] + vel[d], 3.0f));
    }
    float f = pso_fitness(pos, S, G, V, mn_norm, pen_fg, pen_bg);
    if (act && f > pbf) {             // strict, matches `fit > pb_fit`
      pbf = f;
#pragma unroll
      for (int d = 0; d < 6; ++d) pbp[d] = pos[d];
    }
    float bf = pbf; int bl = lane;
    argmax64(bf, bl);                 // uniform result across wave
    if (bf > gbf) {                   // wave-uniform branch; strict `improve`
      gbf = bf;
#pragma unroll
      for (int d = 0; d < 6; ++d) gb[d] = __shfl(pbp[d], bl, 64);
    }
  }

  if (lane == 0) {
    float e0 = expf(gb[0]), e1 = expf(gb[1]), e2 = expf(gb[2]), e3 = expf(gb[3]);
    float fgs = e0 + e1 + 1e-8f, bgs = e2 + e3 + 1e-8f;
    pout[0] = e0 / fgs;  // rgb_fg
    pout[1] = e1 / fgs;  // dep_fg
    pout[2] = e2 / bgs;  // rgb_bg
    pout[3] = e3 / bgs;  // dep_bg
  }
}

// ---------------- Stage D0: per-position fusion coefficients ----------------
__global__ __launch_bounds__(256) void ab_kernel(
    const float* __restrict__ sim_rgb, const float* __restrict__ sim_dep,
    const float* __restrict__ pout, float2* __restrict__ ab) {
  int i = blockIdx.x * 256 + threadIdx.x;  // 0..32767 (b*4096+p)
  float a = pout[0], bb = pout[1], c = pout[2], d = pout[3];
  float s = sim_rgb[i] + sim_dep[i];
  float pr = 1.f / (1.f + expf(-3.f * s));   // sigmoid(3*(rs+ds))
  float2 r;
  r.x = pr * a + (1.f - pr) * c;   // coefficient on f_rgb
  r.y = pr * bb + (1.f - pr) * d;  // coefficient on f_depth
  ab[i] = r;
}

// ---------------- Stage D1: bf16 MFMA GEMM  Out = W x (a*Frgb + b*Fdep), +BN+ReLU
// Per batch b: M=256 (out ch), N=4096 (pos), K=256 (in ch).
// Tile 128x128, BK=32, 4 waves (2x2), 4x4 16x16 frags per wave.
// A = W [m][k] staged K-contiguous, row pad 40 bf16 (80B, 16B-aligned b128 reads).
// B^T = F^T [n][k] staged K-contiguous, row pad 34 bf16 (17-word stride:
//   conflict-free packed-bf16x2 writes; ~2-way b32 frag reads).
// Verified-pattern basis: m92/m97 (A + B^T K-contig, identical per-lane frag
// loads); C/D layout col=lane&15,row=(lane>>4)*4+reg (m89).
__global__ __launch_bounds__(256, 2) void gemm_kernel(
    const float* __restrict__ f_rgb, const float* __restrict__ f_dep,
    const float2* __restrict__ ab, const float* __restrict__ W,
    const float* __restrict__ bn_g, const float* __restrict__ bn_b,
    const float* __restrict__ bn_m, const float* __restrict__ bn_v,
    float* __restrict__ out) {
  __shared__ __align__(16) uint32_t As[128 * 20];  // W tile: [m][k-pairs], stride 20 words
  __shared__ __align__(16) uint32_t Bs[128 * 17];  // F^T tile: [n][k-pairs], stride 17 words
  const int tid = threadIdx.x;
  const int nt = blockIdx.x, mt = blockIdx.y, b = blockIdx.z;
  const int n0 = nt * 128, m0 = mt * 128;
  const size_t fbase = (size_t)b * 256 * 4096;

  // B staging role: thread -> (n within tile, k-half)
  const int bnn = tid & 127, bkh = tid >> 7;
  const float2 abv = ab[b * 4096 + n0 + bnn];
  const float* frb = f_rgb + fbase + n0 + bnn;
  const float* fdb = f_dep + fbase + n0 + bnn;
  // A staging role: thread -> (k-pair, m quarter-row)
  const int ak2 = tid & 15, amq = tid >> 4;
  // wave/frag coords
  const int lane = tid & 63, wv = tid >> 6;
  const int wm = wv >> 1, wn = wv & 1;
  const int lg = lane >> 4, ln = lane & 15;

  f32x4 acc[4][4];
#pragma unroll
  for (int i = 0; i < 4; ++i)
#pragma unroll
    for (int j = 0; j < 4; ++j) acc[i][j] = (f32x4)0.f;

  for (int s = 0; s < 8; ++s) {
    const int k0 = s * 32;
    // ---- stage A (W tile) ----
#pragma unroll
    for (int p = 0; p < 8; ++p) {
      int m = amq + p * 16;
      const float2 w2 = *(const float2*)(W + (size_t)(m0 + m) * 256 + k0 + 2 * ak2);
      As[m * 20 + ak2] = pack_bf2(w2.x, w2.y);
    }
    // ---- stage B (fused feature tile, transposed to [n][k]) ----
#pragma unroll
    for (int q = 0; q < 8; ++q) {
      int kp = bkh * 8 + q;
      size_t ko = (size_t)(k0 + 2 * kp) * 4096;
      float r0 = frb[ko], r1 = frb[ko + 4096];
      float d0 = fdb[ko], d1 = fdb[ko + 4096];
      Bs[bnn * 17 + kp] = pack_bf2(abv.x * r0 + abv.y * d0, abv.x * r1 + abv.y * d1);
    }
    __syncthreads();
    // ---- fragment loads ----
    short8 af[4], bf[4];
#pragma unroll
    for (int i = 0; i < 4; ++i) {
      int m = wm * 64 + i * 16 + ln;
      float4 t = *(const float4*)(&As[m * 20 + lg * 4]);
      af[i] = *(short8*)&t;
    }
#pragma unroll
    for (int j = 0; j < 4; ++j) {
      int n = wn * 64 + j * 16 + ln;
      const uint32_t* bp = &Bs[n * 17 + lg * 4];
      union { uint32_t w[4]; short8 v; } u;
      u.w[0] = bp[0]; u.w[1] = bp[1]; u.w[2] = bp[2]; u.w[3] = bp[3];
      bf[j] = u.v;
    }
    // ---- MFMA ----
#pragma unroll
    for (int i = 0; i < 4; ++i)
#pragma unroll
      for (int j = 0; j < 4; ++j)
        acc[i][j] = __builtin_amdgcn_mfma_f32_16x16x32_bf16(af[i], bf[j], acc[i][j], 0, 0, 0);
    __syncthreads();
  }

  // ---- epilogue: BN + ReLU, coalesced stores (16 lanes = 64B segments) ----
#pragma unroll
  for (int i = 0; i < 4; ++i) {
#pragma unroll
    for (int r = 0; r < 4; ++r) {
      int m = m0 + wm * 64 + i * 16 + lg * 4 + r;
      float inv = bn_g[m] / sqrtf(bn_v[m] + 1e-5f);
      float sh = bn_b[m] - bn_m[m] * inv;
      float* orow = out + ((size_t)(b * 256 + m)) * 4096 + n0 + wn * 64 + ln;
#pragma unroll
      for (int j = 0; j < 4; ++j)
        orow[j * 16] = fmaxf(acc[i][j][r] * inv + sh, 0.f);
    }
  }
}

extern "C" void kernel_launch(void* const* d_in, const int* in_sizes, int n_in,
                              void* d_out, int out_size, void* d_ws, size_t ws_size,
                              hipStream_t stream) {
  (void)in_sizes; (void)n_in; (void)out_size; (void)ws_size;
  const float* f_rgb     = (const float*)d_in[0];
  const float* f_depth   = (const float*)d_in[1];
  // d_in[2] = r_rgb (unused by reference)
  const float* r_depth   = (const float*)d_in[3];
  const float* proto_rgb = (const float*)d_in[4];
  const float* proto_dep = (const float*)d_in[5];
  const float* qmask     = (const float*)d_in[6];
  const float* conv_w    = (const float*)d_in[7];
  const float* bn_g      = (const float*)d_in[8];
  const float* bn_b      = (const float*)d_in[9];
  const float* bn_m      = (const float*)d_in[10];
  const float* bn_v      = (const float*)d_in[11];
  float* out = (float*)d_out;
  float* ws  = (float*)d_ws;

  float* ph_rgb  = ws + WS_PH_RGB;
  float* ph_dep  = ws + WS_PH_DEP;
  float* sim_rgb = ws + WS_SIM_RGB;
  float* sim_dep = ws + WS_SIM_DEP;
  float* npm     = ws + WS_NPMAPS;   // also the RNG buffer after stats_kernel
  float* stats   = ws + WS_STATS;
  float* pout    = ws + WS_POUT;
  float2* ab     = (float2*)(ws + WS_AB);

  proto_kernel<<<dim3(8), dim3(64), 0, stream>>>(proto_rgb, proto_dep, ph_rgb, ph_dep);
  sim_kernel<<<dim3(16, 16), dim3(256), 0, stream>>>(f_rgb, f_depth, ph_rgb, ph_dep,
                                                     sim_rgb, sim_dep);
  npmaps_kernel<<<dim3(16), dim3(256), 0, stream>>>(sim_rgb, sim_dep, qmask, r_depth, npm);
  stats_kernel<<<dim3(1), dim3(256), 0, stream>>>(npm, stats);
  rng_kernel<<<dim3(58), dim3(256), 0, stream>>>(npm);
  pso_kernel<<<dim3(1), dim3(64), 0, stream>>>(stats, npm, pout);
  ab_kernel<<<dim3(128), dim3(256), 0, stream>>>(sim_rgb, sim_dep, pout, ab);
  gemm_kernel<<<dim3(32, 2, 8), dim3(256), 0, stream>>>(f_rgb, f_depth, ab, conv_w,
                                                        bn_g, bn_b, bn_m, bn_v, out);
}

// Round 4
// 92.605 us; speedup vs baseline: 2.5016x; 1.4864x over previous
//
#include <hip/hip_runtime.h>
#include <stdint.h>
#include <float.h>

// Problem geometry: B=8, C=256, H=W=64 (HW=4096). Output [8,256,64,64] f32.
//
// ws layout (float offsets):
static constexpr size_t WS_PH_RGB  = 0;        // (unused now)
static constexpr size_t WS_PH_DEP  = 2048;     // (unused now)
static constexpr size_t WS_SIM_RGB = 4096;     // [8][4096]
static constexpr size_t WS_SIM_DEP = 36864;    // [8][4096]
static constexpr size_t WS_NPMAPS  = 69632;    // np maps [4][4096]
static constexpr size_t WS_STATS   = 86016;    // 27 floats
static constexpr size_t WS_POUT    = 86048;    // 4 floats
static constexpr size_t WS_RNG     = 90112;    // PSO randoms (~15888 floats used)

typedef short short8 __attribute__((ext_vector_type(8)));
typedef float f32x4 __attribute__((ext_vector_type(4)));

// pack two f32 -> two bf16 (RNE) in one u32 (lo = first element)
__device__ __forceinline__ uint32_t pack_bf2(float a, float b) {
  uint32_t ua = __float_as_uint(a), ub = __float_as_uint(b);
  uint32_t ra = (ua + 0x7fffu + ((ua >> 16) & 1u)) >> 16;
  uint32_t rb = (ub + 0x7fffu + ((ub >> 16) & 1u)) >> 16;
  return (ra & 0xffffu) | (rb << 16);
}

// ---------------- JAX threefry2x32 (partitionable semantics) ----------------
__device__ __forceinline__ void threefry2x32(uint32_t k0, uint32_t k1,
                                             uint32_t c0, uint32_t c1,
                                             uint32_t& o0, uint32_t& o1) {
  uint32_t ks2 = k0 ^ k1 ^ 0x1BD11BDAu;
  uint32_t x0 = c0 + k0;
  uint32_t x1 = c1 + k1;
#define TF_ROUND(r) { x0 += x1; x1 = (x1 << (r)) | (x1 >> (32 - (r))); x1 ^= x0; }
  TF_ROUND(13) TF_ROUND(15) TF_ROUND(26) TF_ROUND(6)
  x0 += k1;  x1 += ks2 + 1u;
  TF_ROUND(17) TF_ROUND(29) TF_ROUND(16) TF_ROUND(24)
  x0 += ks2; x1 += k0 + 2u;
  TF_ROUND(13) TF_ROUND(15) TF_ROUND(26) TF_ROUND(6)
  x0 += k0;  x1 += k1 + 3u;
  TF_ROUND(17) TF_ROUND(29) TF_ROUND(16) TF_ROUND(24)
  x0 += k1;  x1 += ks2 + 4u;
  TF_ROUND(13) TF_ROUND(15) TF_ROUND(26) TF_ROUND(6)
  x0 += ks2; x1 += k0 + 5u;
#undef TF_ROUND
  o0 = x0; o1 = x1;
}

__device__ __forceinline__ float tf_u01(uint32_t k0, uint32_t k1, uint32_t idx) {
  uint32_t o0, o1;
  threefry2x32(k0, k1, 0u, idx, o0, o1);
  uint32_t bits = o0 ^ o1;
  uint32_t fb = (bits >> 9) | 0x3F800000u;
  return __uint_as_float(fb) - 1.0f;
}

// ---------------- Stage A1: cosine-sim maps (proto norm folded in) ----------
__global__ __launch_bounds__(256) void sim_kernel(
    const float* __restrict__ f_rgb, const float* __restrict__ f_dep,
    const float* __restrict__ proto_rgb, const float* __restrict__ proto_dep,
    float* __restrict__ sim_rgb, float* __restrict__ sim_dep) {
  int tid = threadIdx.x;
  int bm = blockIdx.y;                 // 16: (b, modality)
  int b = bm >> 1, mo = bm & 1;
  const float* f  = mo ? f_dep : f_rgb;
  const float* pr = mo ? proto_dep : proto_rgb;
  float* sim = mo ? sim_dep : sim_rgb;
  __shared__ float shp[256];
  __shared__ float wsum[4];
  float pv = pr[b * 256 + tid];
  float ss0 = pv * pv;
#pragma unroll
  for (int off = 32; off > 0; off >>= 1) ss0 += __shfl_xor(ss0, off, 64);
  if ((tid & 63) == 0) wsum[tid >> 6] = ss0;
  __syncthreads();
  float nrm = fmaxf(sqrtf(wsum[0] + wsum[1] + wsum[2] + wsum[3]), 1e-12f);
  shp[tid] = pv / nrm;
  __syncthreads();
  int p = blockIdx.x * 256 + tid;      // position within [4096]
  const float* base = f + (size_t)b * 256 * 4096 + p;
  float dot = 0.f, ss = 0.f;
#pragma unroll 8
  for (int c = 0; c < 256; ++c) {
    float x = base[(size_t)c * 4096];  // coalesced across lanes
    dot += x * shp[c];
    ss  += x * x;
  }
  float fn = fmaxf(sqrtf(ss), 1e-12f);
  sim[b * 4096 + p] = dot / fn;
}

// ---------------- Stage A2: batch-mean maps ----------------
__global__ __launch_bounds__(256) void npmaps_kernel(
    const float* __restrict__ sim_rgb, const float* __restrict__ sim_dep,
    const float* __restrict__ qmask, const float* __restrict__ r_dep,
    float* __restrict__ npm) {
  int i = blockIdx.x * 256 + threadIdx.x;  // 0..4095
  float sr = 0.f, sd = 0.f, sm = 0.f, sq = 0.f;
#pragma unroll
  for (int b = 0; b < 8; ++b) {
    sr += sim_rgb[b * 4096 + i];
    sd += sim_dep[b * 4096 + i];
    sm += qmask[b * 4096 + i];
    sq += r_dep[b * 4096 + i];
  }
  npm[i]          = sr * 0.125f;
  npm[4096 + i]   = sd * 0.125f;
  npm[8192 + i]   = sm * 0.125f;
  npm[12288 + i]  = sq * 0.125f;
}

// ---------------- Stage B: PSO sufficient statistics ----------------
__global__ __launch_bounds__(256) void stats_kernel(const float* __restrict__ npm,
                                                    float* __restrict__ stats) {
  const float* np_rgb  = npm;
  const float* np_dep  = npm + 4096;
  const float* np_mask = npm + 8192;
  const float* np_rdep = npm + 12288;
  __shared__ float col[17][257];
  __shared__ float res1[17];
  __shared__ float res2[5];
  int tid = threadIdx.x;
  float acc[17];
#pragma unroll
  for (int k = 0; k < 17; ++k) acc[k] = 0.f;
  for (int i = tid; i < 4096; i += 256) {
    float m = np_mask[i], r = np_rgb[i], d = np_dep[i], q = np_rdep[i];
    float om = 1.f - m;
    float M1 = m * r, M2 = m * d, M3 = om * r, M4 = om * d;
    acc[0] += m;
    acc[1] += M1; acc[2] += M2; acc[3] += M3; acc[4] += M4;
    acc[5] += M1 * M1; acc[6] += M1 * M2; acc[7] += M1 * M3; acc[8] += M1 * M4;
    acc[9] += M2 * M2; acc[10] += M2 * M3; acc[11] += M2 * M4;
    acc[12] += M3 * M3; acc[13] += M3 * M4; acc[14] += M4 * M4;
    float oq = 1.f - q;
    acc[15] += oq * m; acc[16] += oq * om;
  }
#pragma unroll
  for (int k = 0; k < 17; ++k) col[k][tid] = acc[k];
  __syncthreads();
  if (tid < 17) { float s = 0.f; for (int i = 0; i < 256; ++i) s += col[tid][i]; res1[tid] = s; }
  __syncthreads();
  float mask_mean = res1[0] * (1.f / 4096.f);
  float a2[5] = {0.f, 0.f, 0.f, 0.f, 0.f};
  for (int i = tid; i < 4096; i += 256) {
    float m = np_mask[i], r = np_rgb[i], d = np_dep[i];
    float om = 1.f - m;
    float mn = m - mask_mean;
    a2[0] += m * r * mn; a2[1] += m * d * mn;
    a2[2] += om * r * mn; a2[3] += om * d * mn;
    a2[4] += mn * mn;
  }
  __syncthreads();
#pragma unroll
  for (int k = 0; k < 5; ++k) col[k][tid] = a2[k];
  __syncthreads();
  if (tid < 5) { float s = 0.f; for (int i = 0; i < 256; ++i) s += col[tid][i]; res2[tid] = s; }
  __syncthreads();
  if (tid == 0) {
    stats[0] = res1[1]; stats[1] = res1[2]; stats[2] = res1[3]; stats[3] = res1[4];
    float G11 = res1[5], G12 = res1[6], G13 = res1[7], G14 = res1[8];
    float G22 = res1[9], G23 = res1[10], G24 = res1[11];
    float G33 = res1[12], G34 = res1[13], G44 = res1[14];
    float Gf[16] = {G11, G12, G13, G14,  G12, G22, G23, G24,
                    G13, G23, G33, G34,  G14, G24, G34, G44};
    for (int k = 0; k < 16; ++k) stats[4 + k] = Gf[k];
    stats[20] = res2[0]; stats[21] = res2[1]; stats[22] = res2[2]; stats[23] = res2[3];
    stats[24] = sqrtf(res2[4]) + 1e-8f;         // mn_norm (already + EPS)
    stats[25] = res1[15] * (1.f / 4096.f);      // pen_fg
    stats[26] = res1[16] * (1.f / 4096.f);      // pen_bg
  }
}

// ---------------- Stage B2: all PSO randoms, fully parallel ----------------
__global__ __launch_bounds__(256) void rng_kernel(float* __restrict__ rng) {
  int g = blockIdx.x * 256 + threadIdx.x;
  if (g >= 14760) return;
  int kind; uint32_t splitIdx, ctr, dst;
  if (g < 180) {
    kind = 0; splitIdx = 0; ctr = (uint32_t)g; dst = (uint32_t)g;
  } else if (g < 360) {
    kind = 1; splitIdx = 1; ctr = (uint32_t)(g - 180); dst = (uint32_t)g;
  } else if (g < 7560) {
    uint32_t c = (uint32_t)(g - 360);
    kind = 2; splitIdx = 2; ctr = c;
    uint32_t t = c / 180u, rem = c % 180u, p = rem / 6u, d = rem % 6u;
    dst = 360u + t * 360u + p * 12u + d;
  } else {
    uint32_t c = (uint32_t)(g - 7560);
    kind = 3; splitIdx = 3; ctr = c;
    uint32_t t = c / 180u, rem = c % 180u, p = rem / 6u, d = rem % 6u;
    dst = 360u + t * 360u + p * 12u + 6u + d;
  }
  uint32_t k0, k1;
  threefry2x32(0u, 42u, 0u, splitIdx, k0, k1);   // jax.random.split
  float u = tf_u01(k0, k1, ctr);
  float v;
  if (kind == 0)      v = fmaxf(-2.0f, u * 4.0f - 2.0f);   // uniform(-2,2)
  else if (kind == 1) v = fmaxf(-0.5f, u - 0.5f);          // uniform(-0.5,0.5)
  else                v = u;
  rng[dst] = v;
}

// ---------------- Stage C: PSO (one wave; DPP/scalar-path reductions) -------
__device__ __forceinline__ float pso_fitness_fast(const float pos[6],
    const float S[4], const float G[16], const float V[4],
    float mn_norm, float pen_fg, float pen_bg) {
  float e0 = __expf(pos[0]), e1 = __expf(pos[1]);
  float e2 = __expf(pos[2]), e3 = __expf(pos[3]);
  float rf = __builtin_amdgcn_rcpf(e0 + e1 + 1e-8f);
  float rb = __builtin_amdgcn_rcpf(e2 + e3 + 1e-8f);
  float w[4] = {e0 * rf, e1 * rf, e2 * rb, e3 * rb};
  float num = 0.f, mus = 0.f;
#pragma unroll
  for (int k = 0; k < 4; ++k) { num += w[k] * V[k]; mus += w[k] * S[k]; }
  float q = 0.f;
#pragma unroll
  for (int j = 0; j < 4; ++j)
#pragma unroll
    for (int k = 0; k < 4; ++k) q += w[j] * G[j * 4 + k] * w[k];
  float fn2 = fmaxf(q - mus * mus * (1.f / 4096.f), 0.f);
  float den = __builtin_amdgcn_sqrtf(fn2) * mn_norm + 1e-8f;
  float ncc = num * __builtin_amdgcn_rcpf(den);
  return ncc - 0.3f * (w[1] * pen_fg + w[3] * pen_bg);
}

// max over lanes 0..31 (lanes >=32 ignored), all-VALU/scalar path:
// 4x row_ror DPP max within 16-rows, then readlane(0)/readlane(16) + fmax.
__device__ __forceinline__ float wavemax_lo32(float v) {
  int x = __float_as_int(v);
#define DPP_STEP(ctrl) { \
    int y = __builtin_amdgcn_update_dpp(x, x, ctrl, 0xf, 0xf, false); \
    x = __float_as_int(fmaxf(__int_as_float(x), __int_as_float(y))); }
  DPP_STEP(0x128)  // row_ror:8
  DPP_STEP(0x124)  // row_ror:4
  DPP_STEP(0x122)  // row_ror:2
  DPP_STEP(0x121)  // row_ror:1
#undef DPP_STEP
  float r0 = __int_as_float(__builtin_amdgcn_readlane(x, 0));
  float r1 = __int_as_float(__builtin_amdgcn_readlane(x, 16));
  return fmaxf(r0, r1);
}

__global__ void pso_kernel(const float* __restrict__ stats,
                           const float* __restrict__ rng,
                           float* __restrict__ pout) {
  int lane = threadIdx.x;          // 64 threads = 1 wave
  bool act = lane < 30;
  float S[4], G[16], V[4];
#pragma unroll
  for (int k = 0; k < 4; ++k) S[k] = stats[k];
#pragma unroll
  for (int k = 0; k < 16; ++k) G[k] = stats[4 + k];
#pragma unroll
  for (int k = 0; k < 4; ++k) V[k] = stats[20 + k];
  float mn_norm = stats[24], pen_fg = stats[25], pen_bg = stats[26];

  float pos[6], vel[6], pbp[6];
#pragma unroll
  for (int d = 0; d < 6; ++d) { pos[d] = 0.f; vel[d] = 0.f; }
  if (act) {
#pragma unroll
    for (int d = 0; d < 6; ++d) {
      pos[d] = rng[lane * 6 + d];
      vel[d] = rng[180 + lane * 6 + d];
    }
  }
#pragma unroll
  for (int d = 0; d < 6; ++d) pbp[d] = pos[d];

  float f0 = pso_fitness_fast(pos, S, G, V, mn_norm, pen_fg, pen_bg);
  float pbf = act ? f0 : -FLT_MAX;

  // init global best (argmax, ties -> lowest lane, matches jnp.argmax)
  float gbf = wavemax_lo32(pbf);
  float gb[6];
  {
    unsigned long long mm = __ballot(pbf == gbf);
    int bl = __ffsll(mm) - 1;
#pragma unroll
    for (int d = 0; d < 6; ++d)
      gb[d] = __int_as_float(__builtin_amdgcn_readlane(__float_as_int(pbp[d]), bl));
  }

  const float* rbase = rng + 360;
  // depth-2 register prefetch (ping-pong, static indexing)
  float4 A0, A1, A2, B0, B1, B2;
  {
    const float4* p0 = (const float4*)(rbase + lane * 12);
    A0 = p0[0]; A1 = p0[1]; A2 = p0[2];
    const float4* p1 = (const float4*)(rbase + 360 + lane * 12);
    B0 = p1[0]; B1 = p1[1]; B2 = p1[2];
  }

  // prefetch for t up to 41 reads within [360, 360+42*360) -> stays inside
  // the rng region (garbage values never consumed).
#define PSO_ITER(R0, R1, R2, TNEXT) { \
    float r1v[6] = {R0.x, R0.y, R0.z, R0.w, R1.x, R1.y}; \
    float r2v[6] = {R1.z, R1.w, R2.x, R2.y, R2.z, R2.w}; \
    const float4* pf = (const float4*)(rbase + (TNEXT) * 360 + lane * 12); \
    R0 = pf[0]; R1 = pf[1]; R2 = pf[2]; \
    _Pragma("unroll") \
    for (int d = 0; d < 6; ++d) { \
      vel[d] = 0.7f * vel[d] + 1.5f * r1v[d] * (pbp[d] - pos[d]) \
                             + 1.5f * r2v[d] * (gb[d] - pos[d]); \
      pos[d] = fmaxf(-3.0f, fminf(pos[d] + vel[d], 3.0f)); \
    } \
    float f = pso_fitness_fast(pos, S, G, V, mn_norm, pen_fg, pen_bg); \
    if (act && f > pbf) { \
      pbf = f; \
      _Pragma("unroll") for (int d = 0; d < 6; ++d) pbp[d] = pos[d]; \
    } \
    float maxv = wavemax_lo32(pbf); \
    if (maxv > gbf) {    /* wave-uniform branch */ \
      unsigned long long mm = __ballot(pbf == maxv); \
      int bl = __ffsll(mm) - 1; \
      gbf = maxv; \
      _Pragma("unroll") for (int d = 0; d < 6; ++d) \
        gb[d] = __int_as_float(__builtin_amdgcn_readlane(__float_as_int(pbp[d]), bl)); \
    } \
  }

  for (int k = 0; k < 20; ++k) {
    PSO_ITER(A0, A1, A2, 2 * k + 2)
    PSO_ITER(B0, B1, B2, 2 * k + 3)
  }
#undef PSO_ITER

  if (lane == 0) {
    float e0 = expf(gb[0]), e1 = expf(gb[1]), e2 = expf(gb[2]), e3 = expf(gb[3]);
    float fgs = e0 + e1 + 1e-8f, bgs = e2 + e3 + 1e-8f;
    pout[0] = e0 / fgs;  // rgb_fg
    pout[1] = e1 / fgs;  // dep_fg
    pout[2] = e2 / bgs;  // rgb_bg
    pout[3] = e3 / bgs;  // dep_bg
  }
}

// ---------------- Stage D: bf16 MFMA GEMM  Out = W x (a*Frgb + b*Fdep), +BN+ReLU
// ab coefficients computed inline from sim maps + pout (ab_kernel folded in).
// Per batch b: M=256 (out ch), N=4096 (pos), K=256 (in ch).
// Tile 128x128, BK=32, 4 waves (2x2), 4x4 16x16 frags per wave.
__global__ __launch_bounds__(256, 2) void gemm_kernel(
    const float* __restrict__ f_rgb, const float* __restrict__ f_dep,
    const float* __restrict__ sim_rgb, const float* __restrict__ sim_dep,
    const float* __restrict__ pout, const float* __restrict__ W,
    const float* __restrict__ bn_g, const float* __restrict__ bn_b,
    const float* __restrict__ bn_m, const float* __restrict__ bn_v,
    float* __restrict__ out) {
  __shared__ __align__(16) uint32_t As[128 * 20];  // W tile: [m][k-pairs], stride 20 words
  __shared__ __align__(16) uint32_t Bs[128 * 17];  // F^T tile: [n][k-pairs], stride 17 words
  const int tid = threadIdx.x;
  const int nt = blockIdx.x, mt = blockIdx.y, b = blockIdx.z;
  const int n0 = nt * 128, m0 = mt * 128;
  const size_t fbase = (size_t)b * 256 * 4096;

  // B staging role: thread -> (n within tile, k-half)
  const int bnn = tid & 127, bkh = tid >> 7;
  const int gi = b * 4096 + n0 + bnn;
  const float s = sim_rgb[gi] + sim_dep[gi];
  const float prb = 1.f / (1.f + expf(-3.f * s));   // sigmoid(3*(rs+ds))
  const float pa = pout[0], pb = pout[1], pc = pout[2], pd = pout[3];
  const float abx = prb * pa + (1.f - prb) * pc;    // coefficient on f_rgb
  const float aby = prb * pb + (1.f - prb) * pd;    // coefficient on f_depth
  const float* frb = f_rgb + fbase + n0 + bnn;
  const float* fdb = f_dep + fbase + n0 + bnn;
  // A staging role: thread -> (k-pair, m quarter-row)
  const int ak2 = tid & 15, amq = tid >> 4;
  // wave/frag coords
  const int lane = tid & 63, wv = tid >> 6;
  const int wm = wv >> 1, wn = wv & 1;
  const int lg = lane >> 4, ln = lane & 15;

  f32x4 acc[4][4];
#pragma unroll
  for (int i = 0; i < 4; ++i)
#pragma unroll
    for (int j = 0; j < 4; ++j) acc[i][j] = (f32x4)0.f;

  for (int s8 = 0; s8 < 8; ++s8) {
    const int k0 = s8 * 32;
    // ---- stage A (W tile) ----
#pragma unroll
    for (int p = 0; p < 8; ++p) {
      int m = amq + p * 16;
      const float2 w2 = *(const float2*)(W + (size_t)(m0 + m) * 256 + k0 + 2 * ak2);
      As[m * 20 + ak2] = pack_bf2(w2.x, w2.y);
    }
    // ---- stage B (fused feature tile, transposed to [n][k]) ----
#pragma unroll
    for (int q = 0; q < 8; ++q) {
      int kp = bkh * 8 + q;
      size_t ko = (size_t)(k0 + 2 * kp) * 4096;
      float r0 = frb[ko], r1 = frb[ko + 4096];
      float d0 = fdb[ko], d1 = fdb[ko + 4096];
      Bs[bnn * 17 + kp] = pack_bf2(abx * r0 + aby * d0, abx * r1 + aby * d1);
    }
    __syncthreads();
    // ---- fragment loads ----
    short8 af[4], bf[4];
#pragma unroll
    for (int i = 0; i < 4; ++i) {
      int m = wm * 64 + i * 16 + ln;
      float4 t = *(const float4*)(&As[m * 20 + lg * 4]);
      af[i] = *(short8*)&t;
    }
#pragma unroll
    for (int j = 0; j < 4; ++j) {
      int n = wn * 64 + j * 16 + ln;
      const uint32_t* bp = &Bs[n * 17 + lg * 4];
      union { uint32_t w[4]; short8 v; } u;
      u.w[0] = bp[0]; u.w[1] = bp[1]; u.w[2] = bp[2]; u.w[3] = bp[3];
      bf[j] = u.v;
    }
    // ---- MFMA ----
#pragma unroll
    for (int i = 0; i < 4; ++i)
#pragma unroll
      for (int j = 0; j < 4; ++j)
        acc[i][j] = __builtin_amdgcn_mfma_f32_16x16x32_bf16(af[i], bf[j], acc[i][j], 0, 0, 0);
    __syncthreads();
  }

  // ---- epilogue: BN + ReLU, coalesced stores (16 lanes = 64B segments) ----
#pragma unroll
  for (int i = 0; i < 4; ++i) {
#pragma unroll
    for (int r = 0; r < 4; ++r) {
      int m = m0 + wm * 64 + i * 16 + lg * 4 + r;
      float inv = bn_g[m] / sqrtf(bn_v[m] + 1e-5f);
      float sh = bn_b[m] - bn_m[m] * inv;
      float* orow = out + ((size_t)(b * 256 + m)) * 4096 + n0 + wn * 64 + ln;
#pragma unroll
      for (int j = 0; j < 4; ++j)
        orow[j * 16] = fmaxf(acc[i][j][r] * inv + sh, 0.f);
    }
  }
}

extern "C" void kernel_launch(void* const* d_in, const int* in_sizes, int n_in,
                              void* d_out, int out_size, void* d_ws, size_t ws_size,
                              hipStream_t stream) {
  (void)in_sizes; (void)n_in; (void)out_size; (void)ws_size;
  const float* f_rgb     = (const float*)d_in[0];
  const float* f_depth   = (const float*)d_in[1];
  // d_in[2] = r_rgb (unused by reference)
  const float* r_depth   = (const float*)d_in[3];
  const float* proto_rgb = (const float*)d_in[4];
  const float* proto_dep = (const float*)d_in[5];
  const float* qmask     = (const float*)d_in[6];
  const float* conv_w    = (const float*)d_in[7];
  const float* bn_g      = (const float*)d_in[8];
  const float* bn_b      = (const float*)d_in[9];
  const float* bn_m      = (const float*)d_in[10];
  const float* bn_v      = (const float*)d_in[11];
  float* out = (float*)d_out;
  float* ws  = (float*)d_ws;

  float* sim_rgb = ws + WS_SIM_RGB;
  float* sim_dep = ws + WS_SIM_DEP;
  float* npm     = ws + WS_NPMAPS;
  float* stats   = ws + WS_STATS;
  float* pout    = ws + WS_POUT;
  float* rng     = ws + WS_RNG;

  rng_kernel<<<dim3(58), dim3(256), 0, stream>>>(rng);
  sim_kernel<<<dim3(16, 16), dim3(256), 0, stream>>>(f_rgb, f_depth, proto_rgb,
                                                     proto_dep, sim_rgb, sim_dep);
  npmaps_kernel<<<dim3(16), dim3(256), 0, stream>>>(sim_rgb, sim_dep, qmask, r_depth, npm);
  stats_kernel<<<dim3(1), dim3(256), 0, stream>>>(npm, stats);
  pso_kernel<<<dim3(1), dim3(64), 0, stream>>>(stats, rng, pout);
  gemm_kernel<<<dim3(32, 2, 8), dim3(256), 0, stream>>>(f_rgb, f_depth, sim_rgb, sim_dep,
                                                        pout, conv_w,
                                                        bn_g, bn_b, bn_m, bn_v, out);
}

// Round 5
// 91.753 us; speedup vs baseline: 2.5249x; 1.0093x over previous
//
#include <hip/hip_runtime.h>
#include <stdint.h>
#include <float.h>

// Problem geometry: B=8, C=256, H=W=64 (HW=4096). Output [8,256,64,64] f32.
//
// ws layout (float offsets):
static constexpr size_t WS_SIM_RGB = 4096;     // [8][4096]
static constexpr size_t WS_SIM_DEP = 36864;    // [8][4096]
static constexpr size_t WS_NPMAPS  = 69632;    // np maps [4][4096]
static constexpr size_t WS_STATS   = 86016;    // 27 floats
static constexpr size_t WS_POUT    = 86048;    // 4 floats
static constexpr size_t WS_RNG     = 90112;    // PSO randoms (~15888 floats used)

typedef short short8 __attribute__((ext_vector_type(8)));
typedef float f32x4 __attribute__((ext_vector_type(4)));

// pack two f32 -> two bf16 (RNE) in one u32 (lo = first element)
__device__ __forceinline__ uint32_t pack_bf2(float a, float b) {
  uint32_t ua = __float_as_uint(a), ub = __float_as_uint(b);
  uint32_t ra = (ua + 0x7fffu + ((ua >> 16) & 1u)) >> 16;
  uint32_t rb = (ub + 0x7fffu + ((ub >> 16) & 1u)) >> 16;
  return (ra & 0xffffu) | (rb << 16);
}

// ---------------- JAX threefry2x32 (partitionable semantics) ----------------
__device__ __forceinline__ void threefry2x32(uint32_t k0, uint32_t k1,
                                             uint32_t c0, uint32_t c1,
                                             uint32_t& o0, uint32_t& o1) {
  uint32_t ks2 = k0 ^ k1 ^ 0x1BD11BDAu;
  uint32_t x0 = c0 + k0;
  uint32_t x1 = c1 + k1;
#define TF_ROUND(r) { x0 += x1; x1 = (x1 << (r)) | (x1 >> (32 - (r))); x1 ^= x0; }
  TF_ROUND(13) TF_ROUND(15) TF_ROUND(26) TF_ROUND(6)
  x0 += k1;  x1 += ks2 + 1u;
  TF_ROUND(17) TF_ROUND(29) TF_ROUND(16) TF_ROUND(24)
  x0 += ks2; x1 += k0 + 2u;
  TF_ROUND(13) TF_ROUND(15) TF_ROUND(26) TF_ROUND(6)
  x0 += k0;  x1 += k1 + 3u;
  TF_ROUND(17) TF_ROUND(29) TF_ROUND(16) TF_ROUND(24)
  x0 += k1;  x1 += ks2 + 4u;
  TF_ROUND(13) TF_ROUND(15) TF_ROUND(26) TF_ROUND(6)
  x0 += ks2; x1 += k0 + 5u;
#undef TF_ROUND
  o0 = x0; o1 = x1;
}

__device__ __forceinline__ float tf_u01(uint32_t k0, uint32_t k1, uint32_t idx) {
  uint32_t o0, o1;
  threefry2x32(k0, k1, 0u, idx, o0, o1);
  uint32_t bits = o0 ^ o1;
  uint32_t fb = (bits >> 9) | 0x3F800000u;
  return __uint_as_float(fb) - 1.0f;
}

// ---------------- Stage A1: cosine-sim maps (proto norm folded in) ----------
__global__ __launch_bounds__(256) void sim_kernel(
    const float* __restrict__ f_rgb, const float* __restrict__ f_dep,
    const float* __restrict__ proto_rgb, const float* __restrict__ proto_dep,
    float* __restrict__ sim_rgb, float* __restrict__ sim_dep) {
  int tid = threadIdx.x;
  int bm = blockIdx.y;                 // 16: (b, modality)
  int b = bm >> 1, mo = bm & 1;
  const float* f  = mo ? f_dep : f_rgb;
  const float* pr = mo ? proto_dep : proto_rgb;
  float* sim = mo ? sim_dep : sim_rgb;
  __shared__ float shp[256];
  __shared__ float wsum[4];
  float pv = pr[b * 256 + tid];
  float ss0 = pv * pv;
#pragma unroll
  for (int off = 32; off > 0; off >>= 1) ss0 += __shfl_xor(ss0, off, 64);
  if ((tid & 63) == 0) wsum[tid >> 6] = ss0;
  __syncthreads();
  float nrm = fmaxf(sqrtf(wsum[0] + wsum[1] + wsum[2] + wsum[3]), 1e-12f);
  shp[tid] = pv / nrm;
  __syncthreads();
  int p = blockIdx.x * 256 + tid;      // position within [4096]
  const float* base = f + (size_t)b * 256 * 4096 + p;
  float dot = 0.f, ss = 0.f;
#pragma unroll 8
  for (int c = 0; c < 256; ++c) {
    float x = base[(size_t)c * 4096];  // coalesced across lanes
    dot += x * shp[c];
    ss  += x * x;
  }
  float fn = fmaxf(sqrtf(ss), 1e-12f);
  sim[b * 4096 + p] = dot / fn;
}

// ---------------- Stage A2: batch-mean maps ----------------
__global__ __launch_bounds__(256) void npmaps_kernel(
    const float* __restrict__ sim_rgb, const float* __restrict__ sim_dep,
    const float* __restrict__ qmask, const float* __restrict__ r_dep,
    float* __restrict__ npm) {
  int i = blockIdx.x * 256 + threadIdx.x;  // 0..4095
  float sr = 0.f, sd = 0.f, sm = 0.f, sq = 0.f;
#pragma unroll
  for (int b = 0; b < 8; ++b) {
    sr += sim_rgb[b * 4096 + i];
    sd += sim_dep[b * 4096 + i];
    sm += qmask[b * 4096 + i];
    sq += r_dep[b * 4096 + i];
  }
  npm[i]          = sr * 0.125f;
  npm[4096 + i]   = sd * 0.125f;
  npm[8192 + i]   = sm * 0.125f;
  npm[12288 + i]  = sq * 0.125f;
}

// ---------------- Stage B: PSO sufficient statistics ----------------
__global__ __launch_bounds__(256) void stats_kernel(const float* __restrict__ npm,
                                                    float* __restrict__ stats) {
  const float* np_rgb  = npm;
  const float* np_dep  = npm + 4096;
  const float* np_mask = npm + 8192;
  const float* np_rdep = npm + 12288;
  __shared__ float col[17][257];
  __shared__ float res1[17];
  __shared__ float res2[5];
  int tid = threadIdx.x;
  float acc[17];
#pragma unroll
  for (int k = 0; k < 17; ++k) acc[k] = 0.f;
  for (int i = tid; i < 4096; i += 256) {
    float m = np_mask[i], r = np_rgb[i], d = np_dep[i], q = np_rdep[i];
    float om = 1.f - m;
    float M1 = m * r, M2 = m * d, M3 = om * r, M4 = om * d;
    acc[0] += m;
    acc[1] += M1; acc[2] += M2; acc[3] += M3; acc[4] += M4;
    acc[5] += M1 * M1; acc[6] += M1 * M2; acc[7] += M1 * M3; acc[8] += M1 * M4;
    acc[9] += M2 * M2; acc[10] += M2 * M3; acc[11] += M2 * M4;
    acc[12] += M3 * M3; acc[13] += M3 * M4; acc[14] += M4 * M4;
    float oq = 1.f - q;
    acc[15] += oq * m; acc[16] += oq * om;
  }
#pragma unroll
  for (int k = 0; k < 17; ++k) col[k][tid] = acc[k];
  __syncthreads();
  if (tid < 17) { float s = 0.f; for (int i = 0; i < 256; ++i) s += col[tid][i]; res1[tid] = s; }
  __syncthreads();
  float mask_mean = res1[0] * (1.f / 4096.f);
  float a2[5] = {0.f, 0.f, 0.f, 0.f, 0.f};
  for (int i = tid; i < 4096; i += 256) {
    float m = np_mask[i], r = np_rgb[i], d = np_dep[i];
    float om = 1.f - m;
    float mn = m - mask_mean;
    a2[0] += m * r * mn; a2[1] += m * d * mn;
    a2[2] += om * r * mn; a2[3] += om * d * mn;
    a2[4] += mn * mn;
  }
  __syncthreads();
#pragma unroll
  for (int k = 0; k < 5; ++k) col[k][tid] = a2[k];
  __syncthreads();
  if (tid < 5) { float s = 0.f; for (int i = 0; i < 256; ++i) s += col[tid][i]; res2[tid] = s; }
  __syncthreads();
  if (tid == 0) {
    stats[0] = res1[1]; stats[1] = res1[2]; stats[2] = res1[3]; stats[3] = res1[4];
    float G11 = res1[5], G12 = res1[6], G13 = res1[7], G14 = res1[8];
    float G22 = res1[9], G23 = res1[10], G24 = res1[11];
    float G33 = res1[12], G34 = res1[13], G44 = res1[14];
    float Gf[16] = {G11, G12, G13, G14,  G12, G22, G23, G24,
                    G13, G23, G33, G34,  G14, G24, G34, G44};
    for (int k = 0; k < 16; ++k) stats[4 + k] = Gf[k];
    stats[20] = res2[0]; stats[21] = res2[1]; stats[22] = res2[2]; stats[23] = res2[3];
    stats[24] = sqrtf(res2[4]) + 1e-8f;         // mn_norm (already + EPS)
    stats[25] = res1[15] * (1.f / 4096.f);      // pen_fg
    stats[26] = res1[16] * (1.f / 4096.f);      // pen_bg
  }
}

// ---------------- Stage B2: all PSO randoms, fully parallel ----------------
__global__ __launch_bounds__(256) void rng_kernel(float* __restrict__ rng) {
  int g = blockIdx.x * 256 + threadIdx.x;
  if (g >= 14760) return;
  int kind; uint32_t splitIdx, ctr, dst;
  if (g < 180) {
    kind = 0; splitIdx = 0; ctr = (uint32_t)g; dst = (uint32_t)g;
  } else if (g < 360) {
    kind = 1; splitIdx = 1; ctr = (uint32_t)(g - 180); dst = (uint32_t)g;
  } else if (g < 7560) {
    uint32_t c = (uint32_t)(g - 360);
    kind = 2; splitIdx = 2; ctr = c;
    uint32_t t = c / 180u, rem = c % 180u, p = rem / 6u, d = rem % 6u;
    dst = 360u + t * 360u + p * 12u + d;
  } else {
    uint32_t c = (uint32_t)(g - 7560);
    kind = 3; splitIdx = 3; ctr = c;
    uint32_t t = c / 180u, rem = c % 180u, p = rem / 6u, d = rem % 6u;
    dst = 360u + t * 360u + p * 12u + 6u + d;
  }
  uint32_t k0, k1;
  threefry2x32(0u, 42u, 0u, splitIdx, k0, k1);   // jax.random.split
  float u = tf_u01(k0, k1, ctr);
  float v;
  if (kind == 0)      v = fmaxf(-2.0f, u * 4.0f - 2.0f);   // uniform(-2,2)
  else if (kind == 1) v = fmaxf(-0.5f, u - 0.5f);          // uniform(-0.5,0.5)
  else                v = u;
  rng[dst] = v;
}

// ---------------- Stage C: PSO (one wave; DPP/scalar-path reductions) -------
__device__ __forceinline__ float pso_fitness_fast(const float pos[6],
    const float S[4], const float G[16], const float V[4],
    float mn_norm, float pen_fg, float pen_bg) {
  float e0 = __expf(pos[0]), e1 = __expf(pos[1]);
  float e2 = __expf(pos[2]), e3 = __expf(pos[3]);
  float rf = __builtin_amdgcn_rcpf(e0 + e1 + 1e-8f);
  float rb = __builtin_amdgcn_rcpf(e2 + e3 + 1e-8f);
  float w[4] = {e0 * rf, e1 * rf, e2 * rb, e3 * rb};
  float num = 0.f, mus = 0.f;
#pragma unroll
  for (int k = 0; k < 4; ++k) { num += w[k] * V[k]; mus += w[k] * S[k]; }
  float q = 0.f;
#pragma unroll
  for (int j = 0; j < 4; ++j)
#pragma unroll
    for (int k = 0; k < 4; ++k) q += w[j] * G[j * 4 + k] * w[k];
  float fn2 = fmaxf(q - mus * mus * (1.f / 4096.f), 0.f);
  float den = __builtin_amdgcn_sqrtf(fn2) * mn_norm + 1e-8f;
  float ncc = num * __builtin_amdgcn_rcpf(den);
  return ncc - 0.3f * (w[1] * pen_fg + w[3] * pen_bg);
}

// max over lanes 0..31 (lanes >=32 ignored), all-VALU/scalar path.
__device__ __forceinline__ float wavemax_lo32(float v) {
  int x = __float_as_int(v);
#define DPP_STEP(ctrl) { \
    int y = __builtin_amdgcn_update_dpp(x, x, ctrl, 0xf, 0xf, false); \
    x = __float_as_int(fmaxf(__int_as_float(x), __int_as_float(y))); }
  DPP_STEP(0x128)  // row_ror:8
  DPP_STEP(0x124)  // row_ror:4
  DPP_STEP(0x122)  // row_ror:2
  DPP_STEP(0x121)  // row_ror:1
#undef DPP_STEP
  float r0 = __int_as_float(__builtin_amdgcn_readlane(x, 0));
  float r1 = __int_as_float(__builtin_amdgcn_readlane(x, 16));
  return fmaxf(r0, r1);
}

__global__ void pso_kernel(const float* __restrict__ stats,
                           const float* __restrict__ rng,
                           float* __restrict__ pout) {
  int lane = threadIdx.x;          // 64 threads = 1 wave
  bool act = lane < 30;
  float S[4], G[16], V[4];
#pragma unroll
  for (int k = 0; k < 4; ++k) S[k] = stats[k];
#pragma unroll
  for (int k = 0; k < 16; ++k) G[k] = stats[4 + k];
#pragma unroll
  for (int k = 0; k < 4; ++k) V[k] = stats[20 + k];
  float mn_norm = stats[24], pen_fg = stats[25], pen_bg = stats[26];

  float pos[6], vel[6], pbp[6];
#pragma unroll
  for (int d = 0; d < 6; ++d) { pos[d] = 0.f; vel[d] = 0.f; }
  if (act) {
#pragma unroll
    for (int d = 0; d < 6; ++d) {
      pos[d] = rng[lane * 6 + d];
      vel[d] = rng[180 + lane * 6 + d];
    }
  }
#pragma unroll
  for (int d = 0; d < 6; ++d) pbp[d] = pos[d];

  float f0 = pso_fitness_fast(pos, S, G, V, mn_norm, pen_fg, pen_bg);
  float pbf = act ? f0 : -FLT_MAX;

  // init global best (argmax, ties -> lowest lane, matches jnp.argmax)
  float gbf = wavemax_lo32(pbf);
  float gb[6];
  {
    unsigned long long mm = __ballot(pbf == gbf);
    int bl = __ffsll(mm) - 1;
#pragma unroll
    for (int d = 0; d < 6; ++d)
      gb[d] = __int_as_float(__builtin_amdgcn_readlane(__float_as_int(pbp[d]), bl));
  }

  const float* rbase = rng + 360;
  // depth-2 register prefetch (ping-pong, static indexing)
  float4 A0, A1, A2, B0, B1, B2;
  {
    const float4* p0 = (const float4*)(rbase + lane * 12);
    A0 = p0[0]; A1 = p0[1]; A2 = p0[2];
    const float4* p1 = (const float4*)(rbase + 360 + lane * 12);
    B0 = p1[0]; B1 = p1[1]; B2 = p1[2];
  }

#define PSO_ITER(R0, R1, R2, TNEXT) { \
    float r1v[6] = {R0.x, R0.y, R0.z, R0.w, R1.x, R1.y}; \
    float r2v[6] = {R1.z, R1.w, R2.x, R2.y, R2.z, R2.w}; \
    const float4* pf = (const float4*)(rbase + (TNEXT) * 360 + lane * 12); \
    R0 = pf[0]; R1 = pf[1]; R2 = pf[2]; \
    _Pragma("unroll") \
    for (int d = 0; d < 6; ++d) { \
      vel[d] = 0.7f * vel[d] + 1.5f * r1v[d] * (pbp[d] - pos[d]) \
                             + 1.5f * r2v[d] * (gb[d] - pos[d]); \
      pos[d] = fmaxf(-3.0f, fminf(pos[d] + vel[d], 3.0f)); \
    } \
    float f = pso_fitness_fast(pos, S, G, V, mn_norm, pen_fg, pen_bg); \
    if (act && f > pbf) { \
      pbf = f; \
      _Pragma("unroll") for (int d = 0; d < 6; ++d) pbp[d] = pos[d]; \
    } \
    float maxv = wavemax_lo32(pbf); \
    if (maxv > gbf) {    /* wave-uniform branch */ \
      unsigned long long mm = __ballot(pbf == maxv); \
      int bl = __ffsll(mm) - 1; \
      gbf = maxv; \
      _Pragma("unroll") for (int d = 0; d < 6; ++d) \
        gb[d] = __int_as_float(__builtin_amdgcn_readlane(__float_as_int(pbp[d]), bl)); \
    } \
  }

  for (int k = 0; k < 20; ++k) {
    PSO_ITER(A0, A1, A2, 2 * k + 2)
    PSO_ITER(B0, B1, B2, 2 * k + 3)
  }
#undef PSO_ITER

  if (lane == 0) {
    float e0 = expf(gb[0]), e1 = expf(gb[1]), e2 = expf(gb[2]), e3 = expf(gb[3]);
    float fgs = e0 + e1 + 1e-8f, bgs = e2 + e3 + 1e-8f;
    pout[0] = e0 / fgs;  // rgb_fg
    pout[1] = e1 / fgs;  // dep_fg
    pout[2] = e2 / bgs;  // rgb_bg
    pout[3] = e3 / bgs;  // dep_bg
  }
}

// ---------------- Stage D: bf16 MFMA GEMM  Out = W x (a*Frgb + b*Fdep), +BN+ReLU
// Software-pipelined: depth-1 register prefetch of next K-step's global loads
// (issued before current step's MFMA; vmcnt wait lands after the MFMA cluster)
// + LDS double-buffer -> ONE barrier per K-step. Same per-element arithmetic
// as the R4 kernel (pack_bf2 RNE, same MFMA order) -> bit-identical output.
__global__ __launch_bounds__(256, 2) void gemm_kernel(
    const float* __restrict__ f_rgb, const float* __restrict__ f_dep,
    const float* __restrict__ sim_rgb, const float* __restrict__ sim_dep,
    const float* __restrict__ pout, const float* __restrict__ W,
    const float* __restrict__ bn_g, const float* __restrict__ bn_b,
    const float* __restrict__ bn_m, const float* __restrict__ bn_v,
    float* __restrict__ out) {
  __shared__ __align__(16) uint32_t As[2][128 * 20];  // W tile: [m][k-pairs]
  __shared__ __align__(16) uint32_t Bs[2][128 * 17];  // F^T tile: [n][k-pairs]
  const int tid = threadIdx.x;
  const int nt = blockIdx.x, mt = blockIdx.y, b = blockIdx.z;
  const int n0 = nt * 128, m0 = mt * 128;
  const size_t fbase = (size_t)b * 256 * 4096;

  // B staging role: thread -> (n within tile, k-half)
  const int bnn = tid & 127, bkh = tid >> 7;
  const int gi = b * 4096 + n0 + bnn;
  const float s = sim_rgb[gi] + sim_dep[gi];
  const float prb = 1.f / (1.f + expf(-3.f * s));   // sigmoid(3*(rs+ds))
  const float pa = pout[0], pb = pout[1], pc = pout[2], pd = pout[3];
  const float abx = prb * pa + (1.f - prb) * pc;    // coefficient on f_rgb
  const float aby = prb * pb + (1.f - prb) * pd;    // coefficient on f_depth
  const float* frb = f_rgb + fbase + n0 + bnn;
  const float* fdb = f_dep + fbase + n0 + bnn;
  // A staging role: thread -> (k-pair, m quarter-row)
  const int ak2 = tid & 15, amq = tid >> 4;
  // wave/frag coords
  const int lane = tid & 63, wv = tid >> 6;
  const int wm = wv >> 1, wn = wv & 1;
  const int lg = lane >> 4, ln = lane & 15;

  f32x4 acc[4][4];
#pragma unroll
  for (int i = 0; i < 4; ++i)
#pragma unroll
    for (int j = 0; j < 4; ++j) acc[i][j] = (f32x4)0.f;

  // prefetch registers (static indexing)
  float pr0[8], pr1[8], pd0[8], pd1[8];
  float2 pw[8];

#define LOAD_STEP(S) { \
    const int k0_ = (S) * 32; \
    _Pragma("unroll") \
    for (int q = 0; q < 8; ++q) { \
      size_t ko = (size_t)(k0_ + 2 * (bkh * 8 + q)) * 4096; \
      pr0[q] = frb[ko]; pr1[q] = frb[ko + 4096]; \
      pd0[q] = fdb[ko]; pd1[q] = fdb[ko + 4096]; \
    } \
    _Pragma("unroll") \
    for (int p = 0; p < 8; ++p) \
      pw[p] = *(const float2*)(W + (size_t)(m0 + amq + p * 16) * 256 + k0_ + 2 * ak2); \
  }

#define PACK_WRITE(BUF) { \
    _Pragma("unroll") \
    for (int q = 0; q < 8; ++q) \
      Bs[BUF][bnn * 17 + bkh * 8 + q] = \
          pack_bf2(abx * pr0[q] + aby * pd0[q], abx * pr1[q] + aby * pd1[q]); \
    _Pragma("unroll") \
    for (int p = 0; p < 8; ++p) \
      As[BUF][(amq + p * 16) * 20 + ak2] = pack_bf2(pw[p].x, pw[p].y); \
  }

  LOAD_STEP(0)
  PACK_WRITE(0)
  __syncthreads();

  for (int s8 = 0; s8 < 8; ++s8) {
    const int cur = s8 & 1;
    if (s8 < 7) LOAD_STEP(s8 + 1)     // issue next step's loads (no wait yet)
    // ---- fragment loads from current buffer ----
    short8 af[4], bf[4];
#pragma unroll
    for (int i = 0; i < 4; ++i) {
      int m = wm * 64 + i * 16 + ln;
      float4 t = *(const float4*)(&As[cur][m * 20 + lg * 4]);
      af[i] = *(short8*)&t;
    }
#pragma unroll
    for (int j = 0; j < 4; ++j) {
      int n = wn * 64 + j * 16 + ln;
      const uint32_t* bp = &Bs[cur][n * 17 + lg * 4];
      union { uint32_t w[4]; short8 v; } u;
      u.w[0] = bp[0]; u.w[1] = bp[1]; u.w[2] = bp[2]; u.w[3] = bp[3];
      bf[j] = u.v;
    }
    // ---- MFMA (load latency of step s8+1 hides under this) ----
#pragma unroll
    for (int i = 0; i < 4; ++i)
#pragma unroll
      for (int j = 0; j < 4; ++j)
        acc[i][j] = __builtin_amdgcn_mfma_f32_16x16x32_bf16(af[i], bf[j], acc[i][j], 0, 0, 0);
    // ---- pack + write NEXT buffer (vmcnt wait happens here) ----
    if (s8 < 7) PACK_WRITE(cur ^ 1)
    __syncthreads();
  }
#undef LOAD_STEP
#undef PACK_WRITE

  // ---- epilogue: BN + ReLU, coalesced stores (16 lanes = 64B segments) ----
#pragma unroll
  for (int i = 0; i < 4; ++i) {
#pragma unroll
    for (int r = 0; r < 4; ++r) {
      int m = m0 + wm * 64 + i * 16 + lg * 4 + r;
      float inv = bn_g[m] / sqrtf(bn_v[m] + 1e-5f);
      float sh = bn_b[m] - bn_m[m] * inv;
      float* orow = out + ((size_t)(b * 256 + m)) * 4096 + n0 + wn * 64 + ln;
#pragma unroll
      for (int j = 0; j < 4; ++j)
        orow[j * 16] = fmaxf(acc[i][j][r] * inv + sh, 0.f);
    }
  }
}

extern "C" void kernel_launch(void* const* d_in, const int* in_sizes, int n_in,
                              void* d_out, int out_size, void* d_ws, size_t ws_size,
                              hipStream_t stream) {
  (void)in_sizes; (void)n_in; (void)out_size; (void)ws_size;
  const float* f_rgb     = (const float*)d_in[0];
  const float* f_depth   = (const float*)d_in[1];
  // d_in[2] = r_rgb (unused by reference)
  const float* r_depth   = (const float*)d_in[3];
  const float* proto_rgb = (const float*)d_in[4];
  const float* proto_dep = (const float*)d_in[5];
  const float* qmask     = (const float*)d_in[6];
  const float* conv_w    = (const float*)d_in[7];
  const float* bn_g      = (const float*)d_in[8];
  const float* bn_b      = (const float*)d_in[9];
  const float* bn_m      = (const float*)d_in[10];
  const float* bn_v      = (const float*)d_in[11];
  float* out = (float*)d_out;
  float* ws  = (float*)d_ws;

  float* sim_rgb = ws + WS_SIM_RGB;
  float* sim_dep = ws + WS_SIM_DEP;
  float* npm     = ws + WS_NPMAPS;
  float* stats   = ws + WS_STATS;
  float* pout    = ws + WS_POUT;
  float* rng     = ws + WS_RNG;

  rng_kernel<<<dim3(58), dim3(256), 0, stream>>>(rng);
  sim_kernel<<<dim3(16, 16), dim3(256), 0, stream>>>(f_rgb, f_depth, proto_rgb,
                                                     proto_dep, sim_rgb, sim_dep);
  npmaps_kernel<<<dim3(16), dim3(256), 0, stream>>>(sim_rgb, sim_dep, qmask, r_depth, npm);
  stats_kernel<<<dim3(1), dim3(256), 0, stream>>>(npm, stats);
  pso_kernel<<<dim3(1), dim3(64), 0, stream>>>(stats, rng, pout);
  gemm_kernel<<<dim3(32, 2, 8), dim3(256), 0, stream>>>(f_rgb, f_depth, sim_rgb, sim_dep,
                                                        pout, conv_w,
                                                        bn_g, bn_b, bn_m, bn_v, out);
}

// Round 6
// 78.956 us; speedup vs baseline: 2.9341x; 1.1621x over previous
//
#include <hip/hip_runtime.h>
#include <stdint.h>
#include <float.h>

// Problem geometry: B=8, C=256, H=W=64 (HW=4096). Output [8,256,64,64] f32.
//
// ws layout (float offsets):
static constexpr size_t WS_SIM_RGB = 4096;     // [8][4096]
static constexpr size_t WS_SIM_DEP = 36864;    // [8][4096]
static constexpr size_t WS_NPMAPS  = 69632;    // np maps [4][4096]
static constexpr size_t WS_STATS   = 86016;    // 27 floats
static constexpr size_t WS_POUT    = 86048;    // 4 floats
static constexpr size_t WS_RNG     = 90112;    // PSO randoms (~15888 floats used)

typedef short short8 __attribute__((ext_vector_type(8)));
typedef float f32x4 __attribute__((ext_vector_type(4)));

// pack two f32 -> two bf16 (RNE) in one u32 (lo = first element)
__device__ __forceinline__ uint32_t pack_bf2(float a, float b) {
  uint32_t ua = __float_as_uint(a), ub = __float_as_uint(b);
  uint32_t ra = (ua + 0x7fffu + ((ua >> 16) & 1u)) >> 16;
  uint32_t rb = (ub + 0x7fffu + ((ub >> 16) & 1u)) >> 16;
  return (ra & 0xffffu) | (rb << 16);
}

// ---------------- JAX threefry2x32 (partitionable semantics) ----------------
__device__ __forceinline__ void threefry2x32(uint32_t k0, uint32_t k1,
                                             uint32_t c0, uint32_t c1,
                                             uint32_t& o0, uint32_t& o1) {
  uint32_t ks2 = k0 ^ k1 ^ 0x1BD11BDAu;
  uint32_t x0 = c0 + k0;
  uint32_t x1 = c1 + k1;
#define TF_ROUND(r) { x0 += x1; x1 = (x1 << (r)) | (x1 >> (32 - (r))); x1 ^= x0; }
  TF_ROUND(13) TF_ROUND(15) TF_ROUND(26) TF_ROUND(6)
  x0 += k1;  x1 += ks2 + 1u;
  TF_ROUND(17) TF_ROUND(29) TF_ROUND(16) TF_ROUND(24)
  x0 += ks2; x1 += k0 + 2u;
  TF_ROUND(13) TF_ROUND(15) TF_ROUND(26) TF_ROUND(6)
  x0 += k0;  x1 += k1 + 3u;
  TF_ROUND(17) TF_ROUND(29) TF_ROUND(16) TF_ROUND(24)
  x0 += k1;  x1 += ks2 + 4u;
  TF_ROUND(13) TF_ROUND(15) TF_ROUND(26) TF_ROUND(6)
  x0 += ks2; x1 += k0 + 5u;
#undef TF_ROUND
  o0 = x0; o1 = x1;
}

__device__ __forceinline__ float tf_u01(uint32_t k0, uint32_t k1, uint32_t idx) {
  uint32_t o0, o1;
  threefry2x32(k0, k1, 0u, idx, o0, o1);
  uint32_t bits = o0 ^ o1;
  uint32_t fb = (bits >> 9) | 0x3F800000u;
  return __uint_as_float(fb) - 1.0f;
}

// ---------------- Stage A1: cosine-sim maps (proto norm folded in) ----------
__global__ __launch_bounds__(256) void sim_kernel(
    const float* __restrict__ f_rgb, const float* __restrict__ f_dep,
    const float* __restrict__ proto_rgb, const float* __restrict__ proto_dep,
    float* __restrict__ sim_rgb, float* __restrict__ sim_dep) {
  int tid = threadIdx.x;
  int bm = blockIdx.y;                 // 16: (b, modality)
  int b = bm >> 1, mo = bm & 1;
  const float* f  = mo ? f_dep : f_rgb;
  const float* pr = mo ? proto_dep : proto_rgb;
  float* sim = mo ? sim_dep : sim_rgb;
  __shared__ float shp[256];
  __shared__ float wsum[4];
  float pv = pr[b * 256 + tid];
  float ss0 = pv * pv;
#pragma unroll
  for (int off = 32; off > 0; off >>= 1) ss0 += __shfl_xor(ss0, off, 64);
  if ((tid & 63) == 0) wsum[tid >> 6] = ss0;
  __syncthreads();
  float nrm = fmaxf(sqrtf(wsum[0] + wsum[1] + wsum[2] + wsum[3]), 1e-12f);
  shp[tid] = pv / nrm;
  __syncthreads();
  int p = blockIdx.x * 256 + tid;      // position within [4096]
  const float* base = f + (size_t)b * 256 * 4096 + p;
  float dot = 0.f, ss = 0.f;
#pragma unroll 8
  for (int c = 0; c < 256; ++c) {
    float x = base[(size_t)c * 4096];  // coalesced across lanes
    dot += x * shp[c];
    ss  += x * x;
  }
  float fn = fmaxf(sqrtf(ss), 1e-12f);
  sim[b * 4096 + p] = dot / fn;
}

// ---------------- Stage A2: batch-mean maps ----------------
__global__ __launch_bounds__(256) void npmaps_kernel(
    const float* __restrict__ sim_rgb, const float* __restrict__ sim_dep,
    const float* __restrict__ qmask, const float* __restrict__ r_dep,
    float* __restrict__ npm) {
  int i = blockIdx.x * 256 + threadIdx.x;  // 0..4095
  float sr = 0.f, sd = 0.f, sm = 0.f, sq = 0.f;
#pragma unroll
  for (int b = 0; b < 8; ++b) {
    sr += sim_rgb[b * 4096 + i];
    sd += sim_dep[b * 4096 + i];
    sm += qmask[b * 4096 + i];
    sq += r_dep[b * 4096 + i];
  }
  npm[i]          = sr * 0.125f;
  npm[4096 + i]   = sd * 0.125f;
  npm[8192 + i]   = sm * 0.125f;
  npm[12288 + i]  = sq * 0.125f;
}

// ---------------- Stage B: PSO sufficient statistics ----------------
__global__ __launch_bounds__(256) void stats_kernel(const float* __restrict__ npm,
                                                    float* __restrict__ stats) {
  const float* np_rgb  = npm;
  const float* np_dep  = npm + 4096;
  const float* np_mask = npm + 8192;
  const float* np_rdep = npm + 12288;
  __shared__ float col[17][257];
  __shared__ float res1[17];
  __shared__ float res2[5];
  int tid = threadIdx.x;
  float acc[17];
#pragma unroll
  for (int k = 0; k < 17; ++k) acc[k] = 0.f;
  for (int i = tid; i < 4096; i += 256) {
    float m = np_mask[i], r = np_rgb[i], d = np_dep[i], q = np_rdep[i];
    float om = 1.f - m;
    float M1 = m * r, M2 = m * d, M3 = om * r, M4 = om * d;
    acc[0] += m;
    acc[1] += M1; acc[2] += M2; acc[3] += M3; acc[4] += M4;
    acc[5] += M1 * M1; acc[6] += M1 * M2; acc[7] += M1 * M3; acc[8] += M1 * M4;
    acc[9] += M2 * M2; acc[10] += M2 * M3; acc[11] += M2 * M4;
    acc[12] += M3 * M3; acc[13] += M3 * M4; acc[14] += M4 * M4;
    float oq = 1.f - q;
    acc[15] += oq * m; acc[16] += oq * om;
  }
#pragma unroll
  for (int k = 0; k < 17; ++k) col[k][tid] = acc[k];
  __syncthreads();
  if (tid < 17) { float s = 0.f; for (int i = 0; i < 256; ++i) s += col[tid][i]; res1[tid] = s; }
  __syncthreads();
  float mask_mean = res1[0] * (1.f / 4096.f);
  float a2[5] = {0.f, 0.f, 0.f, 0.f, 0.f};
  for (int i = tid; i < 4096; i += 256) {
    float m = np_mask[i], r = np_rgb[i], d = np_dep[i];
    float om = 1.f - m;
    float mn = m - mask_mean;
    a2[0] += m * r * mn; a2[1] += m * d * mn;
    a2[2] += om * r * mn; a2[3] += om * d * mn;
    a2[4] += mn * mn;
  }
  __syncthreads();
#pragma unroll
  for (int k = 0; k < 5; ++k) col[k][tid] = a2[k];
  __syncthreads();
  if (tid < 5) { float s = 0.f; for (int i = 0; i < 256; ++i) s += col[tid][i]; res2[tid] = s; }
  __syncthreads();
  if (tid == 0) {
    stats[0] = res1[1]; stats[1] = res1[2]; stats[2] = res1[3]; stats[3] = res1[4];
    float G11 = res1[5], G12 = res1[6], G13 = res1[7], G14 = res1[8];
    float G22 = res1[9], G23 = res1[10], G24 = res1[11];
    float G33 = res1[12], G34 = res1[13], G44 = res1[14];
    float Gf[16] = {G11, G12, G13, G14,  G12, G22, G23, G24,
                    G13, G23, G33, G34,  G14, G24, G34, G44};
    for (int k = 0; k < 16; ++k) stats[4 + k] = Gf[k];
    stats[20] = res2[0]; stats[21] = res2[1]; stats[22] = res2[2]; stats[23] = res2[3];
    stats[24] = sqrtf(res2[4]) + 1e-8f;         // mn_norm (already + EPS)
    stats[25] = res1[15] * (1.f / 4096.f);      // pen_fg
    stats[26] = res1[16] * (1.f / 4096.f);      // pen_bg
  }
}

// ---------------- Stage B2: all PSO randoms, fully parallel ----------------
__global__ __launch_bounds__(256) void rng_kernel(float* __restrict__ rng) {
  int g = blockIdx.x * 256 + threadIdx.x;
  if (g >= 14760) return;
  int kind; uint32_t splitIdx, ctr, dst;
  if (g < 180) {
    kind = 0; splitIdx = 0; ctr = (uint32_t)g; dst = (uint32_t)g;
  } else if (g < 360) {
    kind = 1; splitIdx = 1; ctr = (uint32_t)(g - 180); dst = (uint32_t)g;
  } else if (g < 7560) {
    uint32_t c = (uint32_t)(g - 360);
    kind = 2; splitIdx = 2; ctr = c;
    uint32_t t = c / 180u, rem = c % 180u, p = rem / 6u, d = rem % 6u;
    dst = 360u + t * 360u + p * 12u + d;
  } else {
    uint32_t c = (uint32_t)(g - 7560);
    kind = 3; splitIdx = 3; ctr = c;
    uint32_t t = c / 180u, rem = c % 180u, p = rem / 6u, d = rem % 6u;
    dst = 360u + t * 360u + p * 12u + 6u + d;
  }
  uint32_t k0, k1;
  threefry2x32(0u, 42u, 0u, splitIdx, k0, k1);   // jax.random.split
  float u = tf_u01(k0, k1, ctr);
  float v;
  if (kind == 0)      v = fmaxf(-2.0f, u * 4.0f - 2.0f);   // uniform(-2,2)
  else if (kind == 1) v = fmaxf(-0.5f, u - 0.5f);          // uniform(-0.5,0.5)
  else                v = u;
  rng[dst] = v;
}

// ---------------- Stage C: PSO (one wave; DPP/scalar-path reductions) -------
__device__ __forceinline__ float pso_fitness_fast(const float pos[6],
    const float S[4], const float G[16], const float V[4],
    float mn_norm, float pen_fg, float pen_bg) {
  float e0 = __expf(pos[0]), e1 = __expf(pos[1]);
  float e2 = __expf(pos[2]), e3 = __expf(pos[3]);
  float rf = __builtin_amdgcn_rcpf(e0 + e1 + 1e-8f);
  float rb = __builtin_amdgcn_rcpf(e2 + e3 + 1e-8f);
  float w[4] = {e0 * rf, e1 * rf, e2 * rb, e3 * rb};
  float num = 0.f, mus = 0.f;
#pragma unroll
  for (int k = 0; k < 4; ++k) { num += w[k] * V[k]; mus += w[k] * S[k]; }
  float q = 0.f;
#pragma unroll
  for (int j = 0; j < 4; ++j)
#pragma unroll
    for (int k = 0; k < 4; ++k) q += w[j] * G[j * 4 + k] * w[k];
  float fn2 = fmaxf(q - mus * mus * (1.f / 4096.f), 0.f);
  float den = __builtin_amdgcn_sqrtf(fn2) * mn_norm + 1e-8f;
  float ncc = num * __builtin_amdgcn_rcpf(den);
  return ncc - 0.3f * (w[1] * pen_fg + w[3] * pen_bg);
}

// max over lanes 0..31 (lanes >=32 ignored), all-VALU/scalar path.
__device__ __forceinline__ float wavemax_lo32(float v) {
  int x = __float_as_int(v);
#define DPP_STEP(ctrl) { \
    int y = __builtin_amdgcn_update_dpp(x, x, ctrl, 0xf, 0xf, false); \
    x = __float_as_int(fmaxf(__int_as_float(x), __int_as_float(y))); }
  DPP_STEP(0x128)  // row_ror:8
  DPP_STEP(0x124)  // row_ror:4
  DPP_STEP(0x122)  // row_ror:2
  DPP_STEP(0x121)  // row_ror:1
#undef DPP_STEP
  float r0 = __int_as_float(__builtin_amdgcn_readlane(x, 0));
  float r1 = __int_as_float(__builtin_amdgcn_readlane(x, 16));
  return fmaxf(r0, r1);
}

__global__ void pso_kernel(const float* __restrict__ stats,
                           const float* __restrict__ rng,
                           float* __restrict__ pout) {
  int lane = threadIdx.x;          // 64 threads = 1 wave
  bool act = lane < 30;
  float S[4], G[16], V[4];
#pragma unroll
  for (int k = 0; k < 4; ++k) S[k] = stats[k];
#pragma unroll
  for (int k = 0; k < 16; ++k) G[k] = stats[4 + k];
#pragma unroll
  for (int k = 0; k < 4; ++k) V[k] = stats[20 + k];
  float mn_norm = stats[24], pen_fg = stats[25], pen_bg = stats[26];

  float pos[6], vel[6], pbp[6];
#pragma unroll
  for (int d = 0; d < 6; ++d) { pos[d] = 0.f; vel[d] = 0.f; }
  if (act) {
#pragma unroll
    for (int d = 0; d < 6; ++d) {
      pos[d] = rng[lane * 6 + d];
      vel[d] = rng[180 + lane * 6 + d];
    }
  }
#pragma unroll
  for (int d = 0; d < 6; ++d) pbp[d] = pos[d];

  float f0 = pso_fitness_fast(pos, S, G, V, mn_norm, pen_fg, pen_bg);
  float pbf = act ? f0 : -FLT_MAX;

  // init global best (argmax, ties -> lowest lane, matches jnp.argmax)
  float gbf = wavemax_lo32(pbf);
  float gb[6];
  {
    unsigned long long mm = __ballot(pbf == gbf);
    int bl = __ffsll(mm) - 1;
#pragma unroll
    for (int d = 0; d < 6; ++d)
      gb[d] = __int_as_float(__builtin_amdgcn_readlane(__float_as_int(pbp[d]), bl));
  }

  const float* rbase = rng + 360;
  // depth-2 register prefetch (ping-pong, static indexing)
  float4 A0, A1, A2, B0, B1, B2;
  {
    const float4* p0 = (const float4*)(rbase + lane * 12);
    A0 = p0[0]; A1 = p0[1]; A2 = p0[2];
    const float4* p1 = (const float4*)(rbase + 360 + lane * 12);
    B0 = p1[0]; B1 = p1[1]; B2 = p1[2];
  }

#define PSO_ITER(R0, R1, R2, TNEXT) { \
    float r1v[6] = {R0.x, R0.y, R0.z, R0.w, R1.x, R1.y}; \
    float r2v[6] = {R1.z, R1.w, R2.x, R2.y, R2.z, R2.w}; \
    const float4* pf = (const float4*)(rbase + (TNEXT) * 360 + lane * 12); \
    R0 = pf[0]; R1 = pf[1]; R2 = pf[2]; \
    _Pragma("unroll") \
    for (int d = 0; d < 6; ++d) { \
      vel[d] = 0.7f * vel[d] + 1.5f * r1v[d] * (pbp[d] - pos[d]) \
                             + 1.5f * r2v[d] * (gb[d] - pos[d]); \
      pos[d] = fmaxf(-3.0f, fminf(pos[d] + vel[d], 3.0f)); \
    } \
    float f = pso_fitness_fast(pos, S, G, V, mn_norm, pen_fg, pen_bg); \
    if (act && f > pbf) { \
      pbf = f; \
      _Pragma("unroll") for (int d = 0; d < 6; ++d) pbp[d] = pos[d]; \
    } \
    float maxv = wavemax_lo32(pbf); \
    if (maxv > gbf) {    /* wave-uniform branch */ \
      unsigned long long mm = __ballot(pbf == maxv); \
      int bl = __ffsll(mm) - 1; \
      gbf = maxv; \
      _Pragma("unroll") for (int d = 0; d < 6; ++d) \
        gb[d] = __int_as_float(__builtin_amdgcn_readlane(__float_as_int(pbp[d]), bl)); \
    } \
  }

  for (int k = 0; k < 20; ++k) {
    PSO_ITER(A0, A1, A2, 2 * k + 2)
    PSO_ITER(B0, B1, B2, 2 * k + 3)
  }
#undef PSO_ITER

  if (lane == 0) {
    float e0 = expf(gb[0]), e1 = expf(gb[1]), e2 = expf(gb[2]), e3 = expf(gb[3]);
    float fgs = e0 + e1 + 1e-8f, bgs = e2 + e3 + 1e-8f;
    pout[0] = e0 / fgs;  // rgb_fg
    pout[1] = e1 / fgs;  // dep_fg
    pout[2] = e2 / bgs;  // rgb_bg
    pout[3] = e3 / bgs;  // dep_bg
  }
}

// ---------------- Stage D: bf16 MFMA GEMM  Out = W x (a*Frgb + b*Fdep), +BN+ReLU
// 8-wave (512-thread) blocks, same 128x128x32 tile -> 16 waves/CU (2x TLP vs
// R5's 8). Per wave: 64x32 sub-tile (4x2 frags, 8 MFMA/step, 32-reg acc).
// Per-thread staging halved (24 prefetch regs). Depth-1 global prefetch +
// LDS double-buffer, one barrier per K-step. Same per-element arithmetic.
__global__ __launch_bounds__(512, 4) void gemm_kernel(
    const float* __restrict__ f_rgb, const float* __restrict__ f_dep,
    const float* __restrict__ sim_rgb, const float* __restrict__ sim_dep,
    const float* __restrict__ pout, const float* __restrict__ W,
    const float* __restrict__ bn_g, const float* __restrict__ bn_b,
    const float* __restrict__ bn_m, const float* __restrict__ bn_v,
    float* __restrict__ out) {
  __shared__ __align__(16) uint32_t As[2][128 * 20];  // W tile: [m][k-pairs]
  __shared__ __align__(16) uint32_t Bs[2][128 * 17];  // F^T tile: [n][k-pairs]
  const int tid = threadIdx.x;
  const int nt = blockIdx.x, mt = blockIdx.y, b = blockIdx.z;
  const int n0 = nt * 128, m0 = mt * 128;
  const size_t fbase = (size_t)b * 256 * 4096;

  // B staging role: thread -> (n within tile, k-quarter)
  const int bnn = tid & 127, bkq = tid >> 7;          // bkq in 0..3
  const int gi = b * 4096 + n0 + bnn;
  const float s = sim_rgb[gi] + sim_dep[gi];
  const float prb = 1.f / (1.f + expf(-3.f * s));     // sigmoid(3*(rs+ds))
  const float pa = pout[0], pb = pout[1], pc = pout[2], pd = pout[3];
  const float abx = prb * pa + (1.f - prb) * pc;      // coefficient on f_rgb
  const float aby = prb * pb + (1.f - prb) * pd;      // coefficient on f_depth
  const float* frb = f_rgb + fbase + n0 + bnn;
  const float* fdb = f_dep + fbase + n0 + bnn;
  // A staging role: thread -> (k-pair, m-row group)
  const int ak2 = tid & 15, amr = tid >> 4;           // amr in 0..31
  // wave/frag coords: 8 waves as 2(m) x 4(n)
  const int lane = tid & 63, wv = tid >> 6;
  const int wm = wv >> 2, wn = wv & 3;
  const int lg = lane >> 4, ln = lane & 15;

  f32x4 acc[4][2];
#pragma unroll
  for (int i = 0; i < 4; ++i)
#pragma unroll
    for (int j = 0; j < 2; ++j) acc[i][j] = (f32x4)0.f;

  // prefetch registers (static indexing)
  float pr0[4], pr1[4], pd0[4], pd1[4];
  float2 pw[4];

#define LOAD_STEP(S) { \
    const int k0_ = (S) * 32; \
    _Pragma("unroll") \
    for (int q = 0; q < 4; ++q) { \
      size_t ko = (size_t)(k0_ + 2 * (bkq * 4 + q)) * 4096; \
      pr0[q] = frb[ko]; pr1[q] = frb[ko + 4096]; \
      pd0[q] = fdb[ko]; pd1[q] = fdb[ko + 4096]; \
    } \
    _Pragma("unroll") \
    for (int p = 0; p < 4; ++p) \
      pw[p] = *(const float2*)(W + (size_t)(m0 + amr + p * 32) * 256 + k0_ + 2 * ak2); \
  }

#define PACK_WRITE(BUF) { \
    _Pragma("unroll") \
    for (int q = 0; q < 4; ++q) \
      Bs[BUF][bnn * 17 + bkq * 4 + q] = \
          pack_bf2(abx * pr0[q] + aby * pd0[q], abx * pr1[q] + aby * pd1[q]); \
    _Pragma("unroll") \
    for (int p = 0; p < 4; ++p) \
      As[BUF][(amr + p * 32) * 20 + ak2] = pack_bf2(pw[p].x, pw[p].y); \
  }

  LOAD_STEP(0)
  PACK_WRITE(0)
  __syncthreads();

  for (int s8 = 0; s8 < 8; ++s8) {
    const int cur = s8 & 1;
    if (s8 < 7) LOAD_STEP(s8 + 1)     // issue next step's loads (no wait yet)
    // ---- fragment loads from current buffer ----
    short8 af[4], bf[2];
#pragma unroll
    for (int i = 0; i < 4; ++i) {
      int m = wm * 64 + i * 16 + ln;
      float4 t = *(const float4*)(&As[cur][m * 20 + lg * 4]);
      af[i] = *(short8*)&t;
    }
#pragma unroll
    for (int j = 0; j < 2; ++j) {
      int n = wn * 32 + j * 16 + ln;
      const uint32_t* bp = &Bs[cur][n * 17 + lg * 4];
      union { uint32_t w[4]; short8 v; } u;
      u.w[0] = bp[0]; u.w[1] = bp[1]; u.w[2] = bp[2]; u.w[3] = bp[3];
      bf[j] = u.v;
    }
    // ---- MFMA (load latency of step s8+1 hides under this) ----
#pragma unroll
    for (int i = 0; i < 4; ++i)
#pragma unroll
      for (int j = 0; j < 2; ++j)
        acc[i][j] = __builtin_amdgcn_mfma_f32_16x16x32_bf16(af[i], bf[j], acc[i][j], 0, 0, 0);
    // ---- pack + write NEXT buffer (vmcnt wait happens here) ----
    if (s8 < 7) PACK_WRITE(cur ^ 1)
    __syncthreads();
  }
#undef LOAD_STEP
#undef PACK_WRITE

  // ---- epilogue: BN + ReLU, coalesced stores (16 lanes = 64B segments) ----
#pragma unroll
  for (int i = 0; i < 4; ++i) {
#pragma unroll
    for (int r = 0; r < 4; ++r) {
      int m = m0 + wm * 64 + i * 16 + lg * 4 + r;
      float inv = bn_g[m] / sqrtf(bn_v[m] + 1e-5f);
      float sh = bn_b[m] - bn_m[m] * inv;
      float* orow = out + ((size_t)(b * 256 + m)) * 4096 + n0 + wn * 32 + ln;
#pragma unroll
      for (int j = 0; j < 2; ++j)
        orow[j * 16] = fmaxf(acc[i][j][r] * inv + sh, 0.f);
    }
  }
}

extern "C" void kernel_launch(void* const* d_in, const int* in_sizes, int n_in,
                              void* d_out, int out_size, void* d_ws, size_t ws_size,
                              hipStream_t stream) {
  (void)in_sizes; (void)n_in; (void)out_size; (void)ws_size;
  const float* f_rgb     = (const float*)d_in[0];
  const float* f_depth   = (const float*)d_in[1];
  // d_in[2] = r_rgb (unused by reference)
  const float* r_depth   = (const float*)d_in[3];
  const float* proto_rgb = (const float*)d_in[4];
  const float* proto_dep = (const float*)d_in[5];
  const float* qmask     = (const float*)d_in[6];
  const float* conv_w    = (const float*)d_in[7];
  const float* bn_g      = (const float*)d_in[8];
  const float* bn_b      = (const float*)d_in[9];
  const float* bn_m      = (const float*)d_in[10];
  const float* bn_v      = (const float*)d_in[11];
  float* out = (float*)d_out;
  float* ws  = (float*)d_ws;

  float* sim_rgb = ws + WS_SIM_RGB;
  float* sim_dep = ws + WS_SIM_DEP;
  float* npm     = ws + WS_NPMAPS;
  float* stats   = ws + WS_STATS;
  float* pout    = ws + WS_POUT;
  float* rng     = ws + WS_RNG;

  rng_kernel<<<dim3(58), dim3(256), 0, stream>>>(rng);
  sim_kernel<<<dim3(16, 16), dim3(256), 0, stream>>>(f_rgb, f_depth, proto_rgb,
                                                     proto_dep, sim_rgb, sim_dep);
  npmaps_kernel<<<dim3(16), dim3(256), 0, stream>>>(sim_rgb, sim_dep, qmask, r_depth, npm);
  stats_kernel<<<dim3(1), dim3(256), 0, stream>>>(npm, stats);
  pso_kernel<<<dim3(1), dim3(64), 0, stream>>>(stats, rng, pout);
  gemm_kernel<<<dim3(32, 2, 8), dim3(512), 0, stream>>>(f_rgb, f_depth, sim_rgb, sim_dep,
                                                        pout, conv_w,
                                                        bn_g, bn_b, bn_m, bn_v, out);
}